// Round 8
// baseline (181.771 us; speedup 1.0000x reference)
//
#include <hip/hip_runtime.h>
#include <math.h>

// Problem constants
#define HW 4096
#define C 320
#define CX 768
#define L 77
#define NB 10
#define NH 8
#define HD 40
#define NINST 8
#define KVC 640
#define SCALE 0.15811388300841898f  // 1/sqrt(40)
#define PSTR 104                    // LDS row stride in halves

typedef _Float16 half8v __attribute__((ext_vector_type(8)));
typedef _Float16 half4v __attribute__((ext_vector_type(4)));
typedef float f32x4 __attribute__((ext_vector_type(4)));

// prep grid segmentation
#define SEG_MASK   16
#define N_CVT1     (2 * HW * C / 4)          // hs float4s
#define N_CVT2     (NB * L * CX / 4)         // ehs float4s
#define SEG_CVT    (((N_CVT1 + N_CVT2) + 255) / 256)
#define SEG_WPACK  240                        // 4 weights x 12 x 5 (early-exit)
#define SEG_VTZ    180                        // 80*48*96/8/256
#define SEG_KPAD   5                          // 30 rows x 40 half8 = 1200
#define NPREP      (SEG_MASK + SEG_CVT + SEG_WPACK + SEG_VTZ + SEG_KPAD)

// ---------------------------------------------------------------------------
// prep: maskw + cvt + weight packs + VTg init (zeros + ones-column at d=40)
// + Kh pad-row zeroing, one dispatch.
// ---------------------------------------------------------------------------
__device__ __forceinline__ float axis_profile(int o, float lo, float hi) {
    float num = 0.f, den = 0.f;
    int j0 = 8 * o - 4;
#pragma unroll
    for (int t = 0; t < 16; ++t) {
        int j = j0 + t;
        float wt = 1.0f - fabsf((float)t - 7.5f) * 0.125f;
        if (j >= 0 && j < 512) {
            den += wt;
            float fj = (float)j;
            if (fj >= lo && fj < hi) num += wt;
        }
    }
    return num / den;
}

__global__ __launch_bounds__(256) void prep_kernel(
        const float* __restrict__ bboxes,
        const float* __restrict__ hs, const float* __restrict__ ehs,
        const float* __restrict__ Wq, const float* __restrict__ Wk,
        const float* __restrict__ Wv, const float* __restrict__ Wo,
        float* __restrict__ wPh, float* __restrict__ wSum,
        _Float16* __restrict__ hsH, _Float16* __restrict__ ehsH,
        _Float16* __restrict__ WqT, _Float16* __restrict__ WkvT,
        _Float16* __restrict__ WoT, _Float16* __restrict__ VTg,
        _Float16* __restrict__ Kh) {
    __shared__ float tile[64][65];
    __shared__ float sw_s[NINST][64];
    __shared__ float sh_s[NINST][4];
    int bx = blockIdx.x, tid = threadIdx.x;

    if (bx < SEG_MASK) {
        int oyb = bx * 4;
        for (int i = tid; i < NINST * 64; i += 256) {
            int n = i >> 6, ox = i & 63;
            float lo = floorf(512.f * bboxes[n * 4 + 0]);
            float hi = floorf(512.f * bboxes[n * 4 + 2]);
            sw_s[n][ox] = axis_profile(ox, lo, hi);
        }
        if (tid < NINST * 4) {
            int n = tid >> 2, oy = tid & 3;
            float lo = floorf(512.f * bboxes[n * 4 + 1]);
            float hi = floorf(512.f * bboxes[n * 4 + 3]);
            sh_s[n][oy] = axis_profile(oyb + oy, lo, hi);
        }
        __syncthreads();
        int oy = tid >> 6, ox = tid & 63;
        int hw = (oyb + oy) * 64 + ox;
        float sum = 0.1f;
        wPh[hw] = 0.1f;
#pragma unroll
        for (int n = 0; n < NINST; ++n) {
            float wv = 10.f * sh_s[n][oy] * sw_s[n][ox];
            wPh[(n + 1) * HW + hw] = wv;
            sum += wv;
        }
        wSum[hw] = sum;
    } else if (bx < SEG_MASK + SEG_CVT) {
        int i = (bx - SEG_MASK) * 256 + tid;
        const float* src; _Float16* dst;
        if (i < N_CVT1) { src = hs; dst = hsH; }
        else if (i < N_CVT1 + N_CVT2) { i -= N_CVT1; src = ehs; dst = ehsH; }
        else return;
        float4 v = ((const float4*)src)[i];
        half4v h = {(_Float16)v.x, (_Float16)v.y, (_Float16)v.z, (_Float16)v.w};
        ((half4v*)dst)[i] = h;
    } else if (bx < SEG_MASK + SEG_CVT + SEG_WPACK) {
        int zz = bx - SEG_MASK - SEG_CVT;
        int z = zz / 60, inner = zz - z * 60;
        int by = inner / 5, bx2 = inner - by * 5;
        const float* W; _Float16* WT; int K;
        if (z == 0)      { W = Wq; WT = WqT; K = C; }
        else if (z == 1) { W = Wk; WT = WkvT; K = CX; }
        else if (z == 2) { W = Wv; WT = WkvT + (size_t)C * CX; K = CX; }
        else             { W = Wo; WT = WoT; K = C; }
        int kt = by * 64;
        if (kt >= K) return;
        int nt = bx2 * 64;
#pragma unroll
        for (int p = 0; p < 16; ++p) {
            int idx = p * 256 + tid;
            int k = idx >> 6, n = idx & 63;
            tile[k][n] = W[(size_t)(kt + k) * C + nt + n];
        }
        __syncthreads();
#pragma unroll
        for (int p = 0; p < 16; ++p) {
            int idx = p * 256 + tid;
            int n = idx >> 6, k = idx & 63;
            WT[(size_t)(nt + n) * K + kt + k] = (_Float16)tile[k][n];
        }
    } else if (bx < SEG_MASK + SEG_CVT + SEG_WPACK + SEG_VTZ) {
        // VTg init: zeros everywhere; d==40 row = 1.0 for key<77 (ones-column
        // -> PV MFMA output col 40 is the softmax denominator for free).
        int i = (bx - SEG_MASK - SEG_CVT - SEG_WPACK) * 256 + tid;  // half8 idx
        int e0 = i * 8;
        int rem = e0 % (48 * 96);
        int d = rem / 96;
        int key0 = rem % 96;
        half8v v;
#pragma unroll
        for (int j = 0; j < 8; ++j)
            v[j] = (_Float16)((d == 40 && (key0 + j) < 77) ? 1.f : 0.f);
        ((half8v*)VTg)[i] = v;
    } else {
        // Kh pad rows (key 77..79 of each batch) = 0 -> score 0 -> p=1,
        // nullified by V zeros + ones-column zeros. 30 rows x 40 half8.
        int i = (bx - SEG_MASK - SEG_CVT - SEG_WPACK - SEG_VTZ) * 256 + tid;
        if (i < 1200) {
            int rowIdx = i / 40, c8 = i - rowIdx * 40;
            int b = rowIdx / 3, k = 77 + rowIdx - (rowIdx / 3) * 3;
            half8v z8 = {(_Float16)0.f,(_Float16)0.f,(_Float16)0.f,(_Float16)0.f,
                         (_Float16)0.f,(_Float16)0.f,(_Float16)0.f,(_Float16)0.f};
            ((half8v*)(Kh + (size_t)(b * 80 + k) * C))[c8] = z8;
        }
    }
}

// ---------------------------------------------------------------------------
// K/V projection. K half -> Kh(800,320), rows b*80+j. V half -> stored
// directly transposed into VTg (b,h,48,96) (d<40 region only).
// ---------------------------------------------------------------------------
__global__ __launch_bounds__(256) void gemm_kv(const _Float16* __restrict__ A,
                                               const _Float16* __restrict__ BT,
                                               _Float16* __restrict__ Kh,
                                               _Float16* __restrict__ VTg) {
    const int K = CX, M = NB * L;
    int lane = threadIdx.x & 63, wave = threadIdx.x >> 6;
    int m0 = blockIdx.y * 64 + wave * 16;
    int n0 = blockIdx.x * 64;
    int lr = lane & 15, kq = (lane >> 4) * 8;
    int arow = m0 + lr; if (arow >= M) arow = M - 1;
    const _Float16* ap = A + (size_t)arow * K + kq;
    const _Float16* bp = BT + (size_t)(n0 + lr) * K + kq;
    f32x4 acc0 = {0.f,0.f,0.f,0.f}, acc1 = acc0, acc2 = acc0, acc3 = acc0;
    for (int k0 = 0; k0 < K; k0 += 32) {
        half8v af = *(const half8v*)(ap + k0);
        half8v b0 = *(const half8v*)(bp + k0);
        half8v b1 = *(const half8v*)(bp + (size_t)16 * K + k0);
        half8v b2 = *(const half8v*)(bp + (size_t)32 * K + k0);
        half8v b3 = *(const half8v*)(bp + (size_t)48 * K + k0);
        acc0 = __builtin_amdgcn_mfma_f32_16x16x32_f16(af, b0, acc0, 0, 0, 0);
        acc1 = __builtin_amdgcn_mfma_f32_16x16x32_f16(af, b1, acc1, 0, 0, 0);
        acc2 = __builtin_amdgcn_mfma_f32_16x16x32_f16(af, b2, acc2, 0, 0, 0);
        acc3 = __builtin_amdgcn_mfma_f32_16x16x32_f16(af, b3, acc3, 0, 0, 0);
    }
    int rb = m0 + ((lane >> 4) << 2);
    f32x4 accs[4] = {acc0, acc1, acc2, acc3};
#pragma unroll
    for (int t = 0; t < 4; ++t) {
        int col = n0 + t * 16 + lr;
#pragma unroll
        for (int r = 0; r < 4; ++r) {
            int row = rb + r;
            if (row < M) {
                int bb = row / 77;
                int key = row - bb * 77;
                if (col < C) {
                    Kh[(size_t)(bb * 80 + key) * C + col] = (_Float16)accs[t][r];
                } else {
                    int ch = col - C;
                    int h = ch / HD;
                    int d = ch - h * HD;
                    VTg[((size_t)(bb * 8 + h) * 48 + d) * 96 + key] = (_Float16)accs[t][r];
                }
            }
        }
    }
}

// ---------------------------------------------------------------------------
// MFMA attention, batch-split across 2 block groups for 2x occupancy:
//   g0: batches 0-3 (uncond + pairs (0,1),(2,3)) -> Xh (uncond + cond partial)
//   g1: batches 4-9 (pairs (4,5),(6,7),(8,9))    -> Xh2 (cond partial)
// Softmax denominator comes free from the PV MFMA via VTg's ones-column at
// d=40 (col 40 of the PV output = row-sum of P); extracted with one bpermute.
// Q-projection fused (phase 1), transposed through the pre-zeroed LDS bufs.
// ---------------------------------------------------------------------------
__global__ __launch_bounds__(256, 4) void attn_mfma(const _Float16* __restrict__ hsH,  // (8192,320)
                                                    const _Float16* __restrict__ WqT,  // (320,320)
                                                    const _Float16* __restrict__ Kh,   // (800,320)
                                                    const _Float16* __restrict__ VTg,  // (80,48,96)
                                                    const float* __restrict__ wPh,     // (9,HW)
                                                    _Float16* __restrict__ Xh,         // (8192,320)
                                                    _Float16* __restrict__ Xh2) {      // (4096,320)
    __shared__ _Float16 plds[4][2][16 * PSTR];
    int wave = threadIdx.x >> 6, lane = threadIdx.x & 63;
    int g    = blockIdx.x & 1;
    int rest = blockIdx.x >> 1;
    int head = rest >> 6;
    int qg   = rest & 63;
    int qrow0 = qg * 64 + wave * 16;
    int c = lane & 15, quad = lane >> 4;
    _Float16* pl0 = &plds[wave][0][0];
    _Float16* pl1 = &plds[wave][1][0];
    half8v zero8 = {(_Float16)0.f,(_Float16)0.f,(_Float16)0.f,(_Float16)0.f,
                    (_Float16)0.f,(_Float16)0.f,(_Float16)0.f,(_Float16)0.f};

    // pre-zero LDS cols 40..95 of all 16 rows, both buffers
#pragma unroll
    for (int i = 0; i < 4; ++i) {
        int idx = i * 64 + lane;
        if (idx < 224) {
            int buf = idx / 112;
            int rem = idx - buf * 112;
            int row = rem / 7, c8 = rem - row * 7;
            *(half8v*)&plds[wave][buf][row * PSTR + 40 + c8 * 8] = zero8;
        }
    }

    // ---- Phase 1: Q projection (g0: uncond->pl0 + cond->pl1; g1: cond only) ----
    {
        const _Float16* au_p = hsH + (size_t)(qrow0 + c) * C + quad * 8;
        const _Float16* ac_p = au_p + (size_t)HW * C;
        f32x4 qa[2][3] = {};
        for (int k0 = 0; k0 < C; k0 += 32) {
            half8v ac = *(const half8v*)(ac_p + k0);
            half8v au = zero8;
            if (g == 0) au = *(const half8v*)(au_p + k0);
#pragma unroll
            for (int t = 0; t < 3; ++t) {
                const _Float16* bp = WqT + (size_t)(head * HD + t * 16 + c) * C + quad * 8 + k0;
                half8v bf = *(const half8v*)bp;
                qa[1][t] = __builtin_amdgcn_mfma_f32_16x16x32_f16(ac, bf, qa[1][t], 0, 0, 0);
                if (g == 0)
                    qa[0][t] = __builtin_amdgcn_mfma_f32_16x16x32_f16(au, bf, qa[0][t], 0, 0, 0);
            }
        }
#pragma unroll
        for (int t = 0; t < 3; ++t) {
            if (t < 2 || c < 8) {
#pragma unroll
                for (int r = 0; r < 4; ++r) {
                    pl1[(quad * 4 + r) * PSTR + t * 16 + c] = (_Float16)qa[1][t][r];
                    if (g == 0)
                        pl0[(quad * 4 + r) * PSTR + t * 16 + c] = (_Float16)qa[0][t][r];
                }
            }
        }
    }
    // intra-wave LDS RAW: in-order DS pipe + compiler waitcnt (r5-r7 verified)
    half8v qa_c0 = *(const half8v*)(pl1 + (size_t)c * PSTR + quad * 8);
    half8v qa_c1 = *(const half8v*)(pl1 + (size_t)c * PSTR + 32 + quad * 8);
    half8v qa_u0 = qa_c0, qa_u1 = qa_c1;
    if (g == 0) {
        qa_u0 = *(const half8v*)(pl0 + (size_t)c * PSTR + quad * 8);
        qa_u1 = *(const half8v*)(pl0 + (size_t)c * PSTR + 32 + quad * 8);
    }

    f32x4 oacc0 = {0.f,0.f,0.f,0.f}, oacc1 = oacc0, oacc2 = oacc0;
    int srcl = (lane & 48) + 8;   // lane holding col 40 (lsum) within own quad

    // ---- Phase 2: batch pairs ----
    int npairs = 2 + g;
    int bstart = g ? 4 : 0;
    for (int p = 0; p < npairs; ++p) {
        int bx = bstart + 2 * p, by = bx + 1;
        bool xu = (g == 0 && p == 0);
        half8v ax0 = xu ? qa_u0 : qa_c0;
        half8v ax1 = xu ? qa_u1 : qa_c1;

        // QK^T both
        f32x4 scx[5], scy[5];
        const _Float16* kbx = Kh + (size_t)(bx * 80 + c) * C + head * HD + quad * 8;
        const _Float16* kby = Kh + (size_t)(by * 80 + c) * C + head * HD + quad * 8;
#pragma unroll
        for (int t = 0; t < 5; ++t) {
            const _Float16* ktx = kbx + (size_t)t * 16 * C;
            const _Float16* kty = kby + (size_t)t * 16 * C;
            half8v bx0 = *(const half8v*)(ktx);
            half8v bx1 = *(const half8v*)(ktx + 32);
            half8v by0 = *(const half8v*)(kty);
            half8v by1 = *(const half8v*)(kty + 32);
            f32x4 ax = {0.f,0.f,0.f,0.f};
            ax = __builtin_amdgcn_mfma_f32_16x16x32_f16(ax0, bx0, ax, 0, 0, 0);
            ax = __builtin_amdgcn_mfma_f32_16x16x32_f16(ax1, bx1, ax, 0, 0, 0);
            scx[t] = ax;
            f32x4 ay = {0.f,0.f,0.f,0.f};
            ay = __builtin_amdgcn_mfma_f32_16x16x32_f16(qa_c0, by0, ay, 0, 0, 0);
            ay = __builtin_amdgcn_mfma_f32_16x16x32_f16(qa_c1, by1, ay, 0, 0, 0);
            scy[t] = ay;
        }

        // exp (no masking needed: pad keys have score 0, self-nullified)
        // P -> LDS (C-layout -> A-layout)
#pragma unroll
        for (int t = 0; t < 5; ++t) {
#pragma unroll
            for (int r = 0; r < 4; ++r) {
                pl0[(quad * 4 + r) * PSTR + t * 16 + c] = (_Float16)__expf(scx[t][r] * SCALE);
                pl1[(quad * 4 + r) * PSTR + t * 16 + c] = (_Float16)__expf(scy[t][r] * SCALE);
            }
        }

        // PV both (col 40 of output = softmax denominator via ones-column)
        half8v pax0 = *(const half8v*)(pl0 + (size_t)c * PSTR + 0  + quad * 8);
        half8v pax1 = *(const half8v*)(pl0 + (size_t)c * PSTR + 32 + quad * 8);
        half8v pax2 = *(const half8v*)(pl0 + (size_t)c * PSTR + 64 + quad * 8);
        half8v pay0 = *(const half8v*)(pl1 + (size_t)c * PSTR + 0  + quad * 8);
        half8v pay1 = *(const half8v*)(pl1 + (size_t)c * PSTR + 32 + quad * 8);
        half8v pay2 = *(const half8v*)(pl1 + (size_t)c * PSTR + 64 + quad * 8);
        const _Float16* vbx = VTg + ((size_t)(bx * 8 + head) * 48 + c) * 96 + quad * 8;
        const _Float16* vby = VTg + ((size_t)(by * 8 + head) * 48 + c) * 96 + quad * 8;
        f32x4 pvx[3], pvy[3];
#pragma unroll
        for (int t = 0; t < 3; ++t) {
            const _Float16* vtx = vbx + (size_t)t * 16 * 96;
            const _Float16* vty = vby + (size_t)t * 16 * 96;
            half8v vx0 = *(const half8v*)(vtx);
            half8v vx1 = *(const half8v*)(vtx + 32);
            half8v vx2 = *(const half8v*)(vtx + 64);
            half8v vy0 = *(const half8v*)(vty);
            half8v vy1 = *(const half8v*)(vty + 32);
            half8v vy2 = *(const half8v*)(vty + 64);
            f32x4 ax = {0.f,0.f,0.f,0.f};
            ax = __builtin_amdgcn_mfma_f32_16x16x32_f16(pax0, vx0, ax, 0, 0, 0);
            ax = __builtin_amdgcn_mfma_f32_16x16x32_f16(pax1, vx1, ax, 0, 0, 0);
            ax = __builtin_amdgcn_mfma_f32_16x16x32_f16(pax2, vx2, ax, 0, 0, 0);
            pvx[t] = ax;
            f32x4 ay = {0.f,0.f,0.f,0.f};
            ay = __builtin_amdgcn_mfma_f32_16x16x32_f16(pay0, vy0, ay, 0, 0, 0);
            ay = __builtin_amdgcn_mfma_f32_16x16x32_f16(pay1, vy1, ay, 0, 0, 0);
            ay = __builtin_amdgcn_mfma_f32_16x16x32_f16(pay2, vy2, ay, 0, 0, 0);
            pvy[t] = ay;
        }

        // extract denominators (col 40 lives at c==8 of tile t=2)
        float lx[4], ly[4];
#pragma unroll
        for (int r = 0; r < 4; ++r) {
            lx[r] = __shfl(pvx[2][r], srcl, 64);
            ly[r] = __shfl(pvy[2][r], srcl, 64);
        }

        // epilogue
        if (xu) {
            float rin[4];
#pragma unroll
            for (int r = 0; r < 4; ++r) rin[r] = 1.0f / lx[r];
#pragma unroll
            for (int t = 0; t < 3; ++t) {
                int col = t * 16 + c;
                if (col < HD) {
#pragma unroll
                    for (int r = 0; r < 4; ++r) {
                        int row = qrow0 + quad * 4 + r;
                        Xh[(size_t)row * C + head * HD + col] = (_Float16)(pvx[t][r] * rin[r]);
                    }
                }
            }
        } else {
            float rfx[4];
#pragma unroll
            for (int r = 0; r < 4; ++r) {
                int row = qrow0 + quad * 4 + r;
                rfx[r] = wPh[(size_t)(bx - 1) * HW + row] / lx[r];
            }
#pragma unroll
            for (int r = 0; r < 4; ++r) {
                oacc0[r] += pvx[0][r] * rfx[r];
                oacc1[r] += pvx[1][r] * rfx[r];
                oacc2[r] += pvx[2][r] * rfx[r];
            }
        }
        {
            float rfy[4];
#pragma unroll
            for (int r = 0; r < 4; ++r) {
                int row = qrow0 + quad * 4 + r;
                rfy[r] = wPh[(size_t)(by - 1) * HW + row] / ly[r];
            }
#pragma unroll
            for (int r = 0; r < 4; ++r) {
                oacc0[r] += pvy[0][r] * rfy[r];
                oacc1[r] += pvy[1][r] * rfy[r];
                oacc2[r] += pvy[2][r] * rfy[r];
            }
        }
    }

    // write cond partial: g0 -> Xh rows 4096.., g1 -> Xh2
    f32x4 oa[3] = {oacc0, oacc1, oacc2};
    _Float16* dst = g ? (Xh2 + (size_t)qrow0 * C)
                      : (Xh + (size_t)(HW + qrow0) * C);
#pragma unroll
    for (int t = 0; t < 3; ++t) {
        int col = t * 16 + c;
        if (col < HD) {
#pragma unroll
            for (int r = 0; r < 4; ++r) {
                dst[(size_t)(quad * 4 + r) * C + head * HD + col] = (_Float16)oa[t][r];
            }
        }
    }
}

// ---------------------------------------------------------------------------
// O-projection f16 MFMA GEMM with fused epilogue; cond rows sum the two
// attention partials (Xh + Xh2) on the fly.
// ---------------------------------------------------------------------------
__global__ __launch_bounds__(256) void gemm_oproj_f16(const _Float16* __restrict__ A,
                                                      const _Float16* __restrict__ A2,
                                                      const _Float16* __restrict__ BT,
                                                      const float* __restrict__ bo,
                                                      const float* __restrict__ wSum,
                                                      float* __restrict__ Out) {
    const int K = C;
    int lane = threadIdx.x & 63, wave = threadIdx.x >> 6;
    int m0 = blockIdx.y * 64 + wave * 16;
    int n0 = blockIdx.x * 64;
    int lr = lane & 15, kq = (lane >> 4) * 8;
    bool cond = (m0 >= HW);
    const _Float16* ap = A + (size_t)(m0 + lr) * K + kq;
    const _Float16* ap2 = cond ? (A2 + (size_t)(m0 - HW + lr) * K + kq) : ap;
    const _Float16* bp = BT + (size_t)(n0 + lr) * K + kq;
    f32x4 acc0 = {0.f,0.f,0.f,0.f}, acc1 = acc0, acc2 = acc0, acc3 = acc0;
    for (int k0 = 0; k0 < K; k0 += 32) {
        half8v af = *(const half8v*)(ap + k0);
        if (cond) {
            half8v af2 = *(const half8v*)(ap2 + k0);
            af = af + af2;
        }
        half8v b0 = *(const half8v*)(bp + k0);
        half8v b1 = *(const half8v*)(bp + (size_t)16 * K + k0);
        half8v b2 = *(const half8v*)(bp + (size_t)32 * K + k0);
        half8v b3 = *(const half8v*)(bp + (size_t)48 * K + k0);
        acc0 = __builtin_amdgcn_mfma_f32_16x16x32_f16(af, b0, acc0, 0, 0, 0);
        acc1 = __builtin_amdgcn_mfma_f32_16x16x32_f16(af, b1, acc1, 0, 0, 0);
        acc2 = __builtin_amdgcn_mfma_f32_16x16x32_f16(af, b2, acc2, 0, 0, 0);
        acc3 = __builtin_amdgcn_mfma_f32_16x16x32_f16(af, b3, acc3, 0, 0, 0);
    }
    int rb = m0 + ((lane >> 4) << 2);
    f32x4 accs[4] = {acc0, acc1, acc2, acc3};
#pragma unroll
    for (int t = 0; t < 4; ++t) {
        int col = n0 + t * 16 + lr;
        float bv = bo[col];
#pragma unroll
        for (int r = 0; r < 4; ++r) {
            int row = rb + r;
            float v = accs[t][r];
            if (row < HW) {
                v += bv;
            } else {
                float ws = wSum[row - HW];
                v = (v + bv * ws) / (ws + 1e-6f);
            }
            Out[(size_t)row * C + col] = v;
        }
    }
}

// ---------------------------------------------------------------------------
// Launch: 4 dispatches.
// ---------------------------------------------------------------------------
extern "C" void kernel_launch(void* const* d_in, const int* in_sizes, int n_in,
                              void* d_out, int out_size, void* d_ws, size_t ws_size,
                              hipStream_t stream) {
    const float* hs   = (const float*)d_in[0];
    const float* ehs  = (const float*)d_in[1];
    const float* bbox = (const float*)d_in[2];
    const float* Wq   = (const float*)d_in[3];
    const float* Wk   = (const float*)d_in[4];
    const float* Wv   = (const float*)d_in[5];
    const float* Wo   = (const float*)d_in[6];
    const float* bo   = (const float*)d_in[7];
    float* out = (float*)d_out;

    float* wPh  = (float*)d_ws;                          // 9*4096
    float* wSum = wPh + (size_t)9 * HW;                  // 4096
    _Float16* hsH  = (_Float16*)(wSum + HW);             // 8192*320
    _Float16* ehsH = hsH + (size_t)2 * HW * C;           // 770*768
    _Float16* WqT  = ehsH + (size_t)NB * L * CX;         // 320*320
    _Float16* WkvT = WqT + (size_t)C * C;                // 640*768
    _Float16* WoT  = WkvT + (size_t)KVC * CX;            // 320*320
    _Float16* Kh   = WoT + (size_t)C * C;                // 800*320
    _Float16* VTg  = Kh + (size_t)800 * C;               // 80*48*96
    _Float16* Xh   = VTg + (size_t)80 * 48 * 96;         // 8192*320
    _Float16* Xh2  = Xh + (size_t)2 * HW * C;            // 4096*320

    prep_kernel<<<dim3(NPREP), 256, 0, stream>>>(bbox, hs, ehs, Wq, Wk, Wv, Wo,
                                                 wPh, wSum, hsH, ehsH, WqT, WkvT, WoT,
                                                 VTg, Kh);
    gemm_kv<<<dim3(KVC / 64, (NB * L + 63) / 64), 256, 0, stream>>>(ehsH, WkvT, Kh, VTg);
    attn_mfma<<<dim3(NH * 64 * 2), 256, 0, stream>>>(hsH, WqT, Kh, VTg, wPh, Xh, Xh2);
    gemm_oproj_f16<<<dim3(C / 64, (2 * HW) / 64), 256, 0, stream>>>(Xh, Xh2, WoT, bo, wSum, out);
}

// Round 9
// 166.992 us; speedup vs baseline: 1.0885x; 1.0885x over previous
//
#include <hip/hip_runtime.h>
#include <math.h>

// Problem constants
#define HW 4096
#define C 320
#define CX 768
#define L 77
#define NB 10
#define NH 8
#define HD 40
#define NINST 8
#define KVC 640
#define SCALE 0.15811388300841898f  // 1/sqrt(40)
#define PSTR 104                    // LDS row stride in halves (2-way banks)

typedef _Float16 half8v __attribute__((ext_vector_type(8)));
typedef _Float16 half4v __attribute__((ext_vector_type(4)));
typedef float f32x4 __attribute__((ext_vector_type(4)));

// prep grid segmentation
#define SEG_MASK   16
#define N_CVT1     (2 * HW * C / 4)
#define N_CVT2     (NB * L * CX / 4)
#define SEG_CVT    (((N_CVT1 + N_CVT2) + 255) / 256)
#define SEG_WPACK  240
#define SEG_VTZ    180                        // 80*48*96/8/256
#define SEG_KPAD   5
#define NPREP      (SEG_MASK + SEG_CVT + SEG_WPACK + SEG_VTZ + SEG_KPAD)

// ---------------------------------------------------------------------------
// prep: maskw + cvt + weight packs + VTg init (zeros + ones-row at d=40)
// + Kh pad-row zeroing, one dispatch.
// ---------------------------------------------------------------------------
__device__ __forceinline__ float axis_profile(int o, float lo, float hi) {
    float num = 0.f, den = 0.f;
    int j0 = 8 * o - 4;
#pragma unroll
    for (int t = 0; t < 16; ++t) {
        int j = j0 + t;
        float wt = 1.0f - fabsf((float)t - 7.5f) * 0.125f;
        if (j >= 0 && j < 512) {
            den += wt;
            float fj = (float)j;
            if (fj >= lo && fj < hi) num += wt;
        }
    }
    return num / den;
}

__global__ __launch_bounds__(256) void prep_kernel(
        const float* __restrict__ bboxes,
        const float* __restrict__ hs, const float* __restrict__ ehs,
        const float* __restrict__ Wq, const float* __restrict__ Wk,
        const float* __restrict__ Wv, const float* __restrict__ Wo,
        float* __restrict__ wPh, float* __restrict__ wSum,
        _Float16* __restrict__ hsH, _Float16* __restrict__ ehsH,
        _Float16* __restrict__ WqT, _Float16* __restrict__ WkvT,
        _Float16* __restrict__ WoT, _Float16* __restrict__ VTg,
        _Float16* __restrict__ Kh) {
    __shared__ float tile[64][65];
    __shared__ float sw_s[NINST][64];
    __shared__ float sh_s[NINST][4];
    int bx = blockIdx.x, tid = threadIdx.x;

    if (bx < SEG_MASK) {
        int oyb = bx * 4;
        for (int i = tid; i < NINST * 64; i += 256) {
            int n = i >> 6, ox = i & 63;
            float lo = floorf(512.f * bboxes[n * 4 + 0]);
            float hi = floorf(512.f * bboxes[n * 4 + 2]);
            sw_s[n][ox] = axis_profile(ox, lo, hi);
        }
        if (tid < NINST * 4) {
            int n = tid >> 2, oy = tid & 3;
            float lo = floorf(512.f * bboxes[n * 4 + 1]);
            float hi = floorf(512.f * bboxes[n * 4 + 3]);
            sh_s[n][oy] = axis_profile(oyb + oy, lo, hi);
        }
        __syncthreads();
        int oy = tid >> 6, ox = tid & 63;
        int hw = (oyb + oy) * 64 + ox;
        float sum = 0.1f;
        wPh[hw] = 0.1f;
#pragma unroll
        for (int n = 0; n < NINST; ++n) {
            float wv = 10.f * sh_s[n][oy] * sw_s[n][ox];
            wPh[(n + 1) * HW + hw] = wv;
            sum += wv;
        }
        wSum[hw] = sum;
    } else if (bx < SEG_MASK + SEG_CVT) {
        int i = (bx - SEG_MASK) * 256 + tid;
        const float* src; _Float16* dst;
        if (i < N_CVT1) { src = hs; dst = hsH; }
        else if (i < N_CVT1 + N_CVT2) { i -= N_CVT1; src = ehs; dst = ehsH; }
        else return;
        float4 v = ((const float4*)src)[i];
        half4v h = {(_Float16)v.x, (_Float16)v.y, (_Float16)v.z, (_Float16)v.w};
        ((half4v*)dst)[i] = h;
    } else if (bx < SEG_MASK + SEG_CVT + SEG_WPACK) {
        int zz = bx - SEG_MASK - SEG_CVT;
        int z = zz / 60, inner = zz - z * 60;
        int by = inner / 5, bx2 = inner - by * 5;
        const float* W; _Float16* WT; int K;
        if (z == 0)      { W = Wq; WT = WqT; K = C; }
        else if (z == 1) { W = Wk; WT = WkvT; K = CX; }
        else if (z == 2) { W = Wv; WT = WkvT + (size_t)C * CX; K = CX; }
        else             { W = Wo; WT = WoT; K = C; }
        int kt = by * 64;
        if (kt >= K) return;
        int nt = bx2 * 64;
#pragma unroll
        for (int p = 0; p < 16; ++p) {
            int idx = p * 256 + tid;
            int k = idx >> 6, n = idx & 63;
            tile[k][n] = W[(size_t)(kt + k) * C + nt + n];
        }
        __syncthreads();
#pragma unroll
        for (int p = 0; p < 16; ++p) {
            int idx = p * 256 + tid;
            int n = idx >> 6, k = idx & 63;
            WT[(size_t)(nt + n) * K + kt + k] = (_Float16)tile[k][n];
        }
    } else if (bx < SEG_MASK + SEG_CVT + SEG_WPACK + SEG_VTZ) {
        // VTg init: zeros; d==40 row = 1.0 for key<77 (ones-row -> PV output
        // row 40 = softmax denominator for free).
        int i = (bx - SEG_MASK - SEG_CVT - SEG_WPACK) * 256 + tid;
        int e0 = i * 8;
        int rem = e0 % (48 * 96);
        int d = rem / 96;
        int key0 = rem % 96;
        half8v v;
#pragma unroll
        for (int j = 0; j < 8; ++j)
            v[j] = (_Float16)((d == 40 && (key0 + j) < 77) ? 1.f : 0.f);
        ((half8v*)VTg)[i] = v;
    } else {
        // Kh pad rows (key 77..79) = 0 -> score 0 -> p=1, nullified by V/ones zeros.
        int i = (bx - SEG_MASK - SEG_CVT - SEG_WPACK - SEG_VTZ) * 256 + tid;
        if (i < 1200) {
            int rowIdx = i / 40, c8 = i - rowIdx * 40;
            int b = rowIdx / 3, k = 77 + rowIdx - (rowIdx / 3) * 3;
            half8v z8 = {(_Float16)0.f,(_Float16)0.f,(_Float16)0.f,(_Float16)0.f,
                         (_Float16)0.f,(_Float16)0.f,(_Float16)0.f,(_Float16)0.f};
            ((half8v*)(Kh + (size_t)(b * 80 + k) * C))[c8] = z8;
        }
    }
}

// ---------------------------------------------------------------------------
// K/V projection. K half -> Kh(800,320); V half -> directly transposed VTg.
// ---------------------------------------------------------------------------
__global__ __launch_bounds__(256) void gemm_kv(const _Float16* __restrict__ A,
                                               const _Float16* __restrict__ BT,
                                               _Float16* __restrict__ Kh,
                                               _Float16* __restrict__ VTg) {
    const int K = CX, M = NB * L;
    int lane = threadIdx.x & 63, wave = threadIdx.x >> 6;
    int m0 = blockIdx.y * 64 + wave * 16;
    int n0 = blockIdx.x * 64;
    int lr = lane & 15, kq = (lane >> 4) * 8;
    int arow = m0 + lr; if (arow >= M) arow = M - 1;
    const _Float16* ap = A + (size_t)arow * K + kq;
    const _Float16* bp = BT + (size_t)(n0 + lr) * K + kq;
    f32x4 acc0 = {0.f,0.f,0.f,0.f}, acc1 = acc0, acc2 = acc0, acc3 = acc0;
    for (int k0 = 0; k0 < K; k0 += 32) {
        half8v af = *(const half8v*)(ap + k0);
        half8v b0 = *(const half8v*)(bp + k0);
        half8v b1 = *(const half8v*)(bp + (size_t)16 * K + k0);
        half8v b2 = *(const half8v*)(bp + (size_t)32 * K + k0);
        half8v b3 = *(const half8v*)(bp + (size_t)48 * K + k0);
        acc0 = __builtin_amdgcn_mfma_f32_16x16x32_f16(af, b0, acc0, 0, 0, 0);
        acc1 = __builtin_amdgcn_mfma_f32_16x16x32_f16(af, b1, acc1, 0, 0, 0);
        acc2 = __builtin_amdgcn_mfma_f32_16x16x32_f16(af, b2, acc2, 0, 0, 0);
        acc3 = __builtin_amdgcn_mfma_f32_16x16x32_f16(af, b3, acc3, 0, 0, 0);
    }
    int rb = m0 + ((lane >> 4) << 2);
    f32x4 accs[4] = {acc0, acc1, acc2, acc3};
#pragma unroll
    for (int t = 0; t < 4; ++t) {
        int col = n0 + t * 16 + lr;
#pragma unroll
        for (int r = 0; r < 4; ++r) {
            int row = rb + r;
            if (row < M) {
                int bb = row / 77;
                int key = row - bb * 77;
                if (col < C) {
                    Kh[(size_t)(bb * 80 + key) * C + col] = (_Float16)accs[t][r];
                } else {
                    int ch = col - C;
                    int h = ch / HD;
                    int d = ch - h * HD;
                    VTg[((size_t)(bb * 8 + h) * 48 + d) * 96 + key] = (_Float16)accs[t][r];
                }
            }
        }
    }
}

// ---------------------------------------------------------------------------
// MFMA attention, transposed dataflow (r8 post-mortem: occupancy didn't help
// -> shorten the per-wave chain). S^T = K·Q^T and O^T = V^T·P^T via operand
// swap: fragment loads are byte-identical, but each lane owns ONE query row
// with 4 consecutive keys/d per reg quad, so:
//   - Q/P transposes: ds_write_b64 (was scalar b16), reads ds_read_b128
//   - denominator: ones-row at d=40 -> 1 shfl per matrix
//   - wPh: 1 load per matrix/pair; epilogue: 8B vector stores
// SCALE folded into Q at phase-1. 512 blocks, wave = 16 q-rows, 5 batch
// pairs per wave (x,y dual chains for ILP).
// ---------------------------------------------------------------------------
__global__ __launch_bounds__(256, 2) void attn_mfma(const _Float16* __restrict__ hsH,  // (8192,320)
                                                    const _Float16* __restrict__ WqT,  // (320,320)
                                                    const _Float16* __restrict__ Kh,   // (800,320)
                                                    const _Float16* __restrict__ VTg,  // (80,48,96)
                                                    const float* __restrict__ wPh,     // (9,HW)
                                                    _Float16* __restrict__ Xh) {       // (8192,320)
    __shared__ _Float16 plds[4][2][16 * PSTR];
    int wave = threadIdx.x >> 6, lane = threadIdx.x & 63;
    int head = blockIdx.x >> 6;
    int qg = blockIdx.x & 63;
    int qrow0 = qg * 64 + wave * 16;
    int c = lane & 15, quad = lane >> 4;
    _Float16* pl0 = &plds[wave][0][0];
    _Float16* pl1 = &plds[wave][1][0];
    half8v zero8 = {(_Float16)0.f,(_Float16)0.f,(_Float16)0.f,(_Float16)0.f,
                    (_Float16)0.f,(_Float16)0.f,(_Float16)0.f,(_Float16)0.f};

    // prologue: zero halves [row][40..95] in both buffers (224 b128 writes)
#pragma unroll
    for (int i = 0; i < 4; ++i) {
        int idx = i * 64 + lane;
        if (idx < 224) {
            int buf = idx / 112;
            int rem = idx - buf * 112;
            int row = rem / 7, ch = rem - row * 7;
            *(half8v*)&plds[wave][buf][row * PSTR + 40 + ch * 8] = zero8;
        }
    }

    // ---- Phase 1: Q^T projection: A=WqT rows (d), B=hs rows (qrow) ----
    // acc: col=qrow (lane&15), row=d (quad*4+r) -> lane holds 4 consecutive d
    {
        const _Float16* bu = hsH + (size_t)(qrow0 + c) * C + quad * 8;
        const _Float16* bc = bu + (size_t)HW * C;
        f32x4 qa0[3] = {}, qa1[3] = {};
        for (int k0 = 0; k0 < C; k0 += 32) {
            half8v hu = *(const half8v*)(bu + k0);
            half8v hc = *(const half8v*)(bc + k0);
#pragma unroll
            for (int t = 0; t < 3; ++t) {
                const _Float16* ap = WqT + (size_t)(head * HD + t * 16 + c) * C + quad * 8 + k0;
                half8v af = *(const half8v*)ap;
                qa0[t] = __builtin_amdgcn_mfma_f32_16x16x32_f16(af, hu, qa0[t], 0, 0, 0);
                qa1[t] = __builtin_amdgcn_mfma_f32_16x16x32_f16(af, hc, qa1[t], 0, 0, 0);
            }
        }
        // write Qt[qrow][d] (scaled); skip garbage d>=40 (t==2, quad>=2)
#pragma unroll
        for (int t = 0; t < 3; ++t) {
            if (t < 2 || quad < 2) {
                half4v h0 = {(_Float16)(qa0[t][0] * SCALE), (_Float16)(qa0[t][1] * SCALE),
                             (_Float16)(qa0[t][2] * SCALE), (_Float16)(qa0[t][3] * SCALE)};
                half4v h1 = {(_Float16)(qa1[t][0] * SCALE), (_Float16)(qa1[t][1] * SCALE),
                             (_Float16)(qa1[t][2] * SCALE), (_Float16)(qa1[t][3] * SCALE)};
                *(half4v*)(pl0 + c * PSTR + t * 16 + quad * 4) = h0;
                *(half4v*)(pl1 + c * PSTR + t * 16 + quad * 4) = h1;
            }
        }
    }
    // intra-wave LDS RAW: in-order DS pipe + compiler waitcnt (r5-r8 verified)
    half8v qu0 = *(const half8v*)(pl0 + (size_t)c * PSTR + quad * 8);
    half8v qu1 = *(const half8v*)(pl0 + (size_t)c * PSTR + 32 + quad * 8);
    half8v qc0 = *(const half8v*)(pl1 + (size_t)c * PSTR + quad * 8);
    half8v qc1 = *(const half8v*)(pl1 + (size_t)c * PSTR + 32 + quad * 8);

    f32x4 oacc[3] = {};
    int srcl = 32 + c;   // lane holding O^T row d=40 (denominator) for qrow c

    // ---- Phase 2: batch pairs (0,1),(2,3),(4,5),(6,7),(8,9) ----
    for (int p = 0; p < 5; ++p) {
        int bx = 2 * p, by = bx + 1;
        half8v ax0 = p ? qc0 : qu0;
        half8v ax1 = p ? qc1 : qu1;

        // QK^T: A=K rows (key), B=Q -> S^T col=qrow, rows=keys
        const _Float16* kbx = Kh + (size_t)(bx * 80 + c) * C + head * HD + quad * 8;
        const _Float16* kby = Kh + (size_t)(by * 80 + c) * C + head * HD + quad * 8;
        f32x4 sx[5], sy[5];
#pragma unroll
        for (int u = 0; u < 5; ++u) {
            const _Float16* kx = kbx + (size_t)u * 16 * C;
            const _Float16* ky = kby + (size_t)u * 16 * C;
            half8v kx0 = *(const half8v*)(kx);
            half8v kx1 = *(const half8v*)(kx + 32);
            half8v ky0 = *(const half8v*)(ky);
            half8v ky1 = *(const half8v*)(ky + 32);
            f32x4 a = {0.f,0.f,0.f,0.f};
            a = __builtin_amdgcn_mfma_f32_16x16x32_f16(kx0, ax0, a, 0, 0, 0);
            a = __builtin_amdgcn_mfma_f32_16x16x32_f16(kx1, ax1, a, 0, 0, 0);
            sx[u] = a;
            f32x4 b = {0.f,0.f,0.f,0.f};
            b = __builtin_amdgcn_mfma_f32_16x16x32_f16(ky0, qc0, b, 0, 0, 0);
            b = __builtin_amdgcn_mfma_f32_16x16x32_f16(ky1, qc1, b, 0, 0, 0);
            sy[u] = b;
        }

        // exp (scale pre-folded) + P^T -> LDS: one ds_write_b64 per tile
#pragma unroll
        for (int u = 0; u < 5; ++u) {
            half4v hx = {(_Float16)__expf(sx[u][0]), (_Float16)__expf(sx[u][1]),
                         (_Float16)__expf(sx[u][2]), (_Float16)__expf(sx[u][3])};
            half4v hy = {(_Float16)__expf(sy[u][0]), (_Float16)__expf(sy[u][1]),
                         (_Float16)__expf(sy[u][2]), (_Float16)__expf(sy[u][3])};
            *(half4v*)(pl0 + c * PSTR + u * 16 + quad * 4) = hx;
            *(half4v*)(pl1 + c * PSTR + u * 16 + quad * 4) = hy;
        }

        // P^T B-fragments: 3 ds_read_b128 per matrix
        half8v px0 = *(const half8v*)(pl0 + (size_t)c * PSTR + 0  + quad * 8);
        half8v px1 = *(const half8v*)(pl0 + (size_t)c * PSTR + 32 + quad * 8);
        half8v px2 = *(const half8v*)(pl0 + (size_t)c * PSTR + 64 + quad * 8);
        half8v py0 = *(const half8v*)(pl1 + (size_t)c * PSTR + 0  + quad * 8);
        half8v py1 = *(const half8v*)(pl1 + (size_t)c * PSTR + 32 + quad * 8);
        half8v py2 = *(const half8v*)(pl1 + (size_t)c * PSTR + 64 + quad * 8);

        // PV: A=V^T rows (d), B=P^T -> O^T col=qrow, rows=d
        const _Float16* vbx = VTg + ((size_t)(bx * 8 + head) * 48 + c) * 96 + quad * 8;
        const _Float16* vby = VTg + ((size_t)(by * 8 + head) * 48 + c) * 96 + quad * 8;
        f32x4 ox[3], oy[3];
#pragma unroll
        for (int t = 0; t < 3; ++t) {
            const _Float16* vx = vbx + (size_t)t * 16 * 96;
            const _Float16* vy = vby + (size_t)t * 16 * 96;
            half8v vx0 = *(const half8v*)(vx);
            half8v vx1 = *(const half8v*)(vx + 32);
            half8v vx2 = *(const half8v*)(vx + 64);
            half8v vy0 = *(const half8v*)(vy);
            half8v vy1 = *(const half8v*)(vy + 32);
            half8v vy2 = *(const half8v*)(vy + 64);
            f32x4 a = {0.f,0.f,0.f,0.f};
            a = __builtin_amdgcn_mfma_f32_16x16x32_f16(vx0, px0, a, 0, 0, 0);
            a = __builtin_amdgcn_mfma_f32_16x16x32_f16(vx1, px1, a, 0, 0, 0);
            a = __builtin_amdgcn_mfma_f32_16x16x32_f16(vx2, px2, a, 0, 0, 0);
            ox[t] = a;
            f32x4 b = {0.f,0.f,0.f,0.f};
            b = __builtin_amdgcn_mfma_f32_16x16x32_f16(vy0, py0, b, 0, 0, 0);
            b = __builtin_amdgcn_mfma_f32_16x16x32_f16(vy1, py1, b, 0, 0, 0);
            b = __builtin_amdgcn_mfma_f32_16x16x32_f16(vy2, py2, b, 0, 0, 0);
            oy[t] = b;
        }

        // denominators: O^T row d=40 = tile2 reg0 at quad 2 -> one shfl each
        float lx = __shfl(ox[2][0], srcl, 64);
        float ly = __shfl(oy[2][0], srcl, 64);

        if (p == 0) {
            float rin = 1.0f / lx;
#pragma unroll
            for (int t = 0; t < 3; ++t) {
                if (t < 2 || quad < 2) {
                    half4v h = {(_Float16)(ox[t][0] * rin), (_Float16)(ox[t][1] * rin),
                                (_Float16)(ox[t][2] * rin), (_Float16)(ox[t][3] * rin)};
                    *(half4v*)(Xh + (size_t)(qrow0 + c) * C + head * HD + t * 16 + quad * 4) = h;
                }
            }
        } else {
            float rfx = wPh[(size_t)(bx - 1) * HW + qrow0 + c] / lx;
#pragma unroll
            for (int t = 0; t < 3; ++t) {
                oacc[t][0] += ox[t][0] * rfx;
                oacc[t][1] += ox[t][1] * rfx;
                oacc[t][2] += ox[t][2] * rfx;
                oacc[t][3] += ox[t][3] * rfx;
            }
        }
        {
            float rfy = wPh[(size_t)(by - 1) * HW + qrow0 + c] / ly;
#pragma unroll
            for (int t = 0; t < 3; ++t) {
                oacc[t][0] += oy[t][0] * rfy;
                oacc[t][1] += oy[t][1] * rfy;
                oacc[t][2] += oy[t][2] * rfy;
                oacc[t][3] += oy[t][3] * rfy;
            }
        }
    }

    // write fused cond rows (8B vector stores)
#pragma unroll
    for (int t = 0; t < 3; ++t) {
        if (t < 2 || quad < 2) {
            half4v h = {(_Float16)oacc[t][0], (_Float16)oacc[t][1],
                        (_Float16)oacc[t][2], (_Float16)oacc[t][3]};
            *(half4v*)(Xh + (size_t)(HW + qrow0 + c) * C + head * HD + t * 16 + quad * 4) = h;
        }
    }
}

// ---------------------------------------------------------------------------
// O-projection f16 MFMA GEMM with fused epilogue.
// ---------------------------------------------------------------------------
__global__ __launch_bounds__(256) void gemm_oproj_f16(const _Float16* __restrict__ A,
                                                      const _Float16* __restrict__ BT,
                                                      const float* __restrict__ bo,
                                                      const float* __restrict__ wSum,
                                                      float* __restrict__ Out) {
    const int K = C;
    int lane = threadIdx.x & 63, wave = threadIdx.x >> 6;
    int m0 = blockIdx.y * 64 + wave * 16;
    int n0 = blockIdx.x * 64;
    int lr = lane & 15, kq = (lane >> 4) * 8;
    const _Float16* ap = A + (size_t)(m0 + lr) * K + kq;
    const _Float16* bp = BT + (size_t)(n0 + lr) * K + kq;
    f32x4 acc0 = {0.f,0.f,0.f,0.f}, acc1 = acc0, acc2 = acc0, acc3 = acc0;
    for (int k0 = 0; k0 < K; k0 += 32) {
        half8v af = *(const half8v*)(ap + k0);
        half8v b0 = *(const half8v*)(bp + k0);
        half8v b1 = *(const half8v*)(bp + (size_t)16 * K + k0);
        half8v b2 = *(const half8v*)(bp + (size_t)32 * K + k0);
        half8v b3 = *(const half8v*)(bp + (size_t)48 * K + k0);
        acc0 = __builtin_amdgcn_mfma_f32_16x16x32_f16(af, b0, acc0, 0, 0, 0);
        acc1 = __builtin_amdgcn_mfma_f32_16x16x32_f16(af, b1, acc1, 0, 0, 0);
        acc2 = __builtin_amdgcn_mfma_f32_16x16x32_f16(af, b2, acc2, 0, 0, 0);
        acc3 = __builtin_amdgcn_mfma_f32_16x16x32_f16(af, b3, acc3, 0, 0, 0);
    }
    int rb = m0 + ((lane >> 4) << 2);
    f32x4 accs[4] = {acc0, acc1, acc2, acc3};
#pragma unroll
    for (int t = 0; t < 4; ++t) {
        int col = n0 + t * 16 + lr;
        float bv = bo[col];
#pragma unroll
        for (int r = 0; r < 4; ++r) {
            int row = rb + r;
            float v = accs[t][r];
            if (row < HW) {
                v += bv;
            } else {
                float ws = wSum[row - HW];
                v = (v + bv * ws) / (ws + 1e-6f);
            }
            Out[(size_t)row * C + col] = v;
        }
    }
}

// ---------------------------------------------------------------------------
// Launch: 4 dispatches.
// ---------------------------------------------------------------------------
extern "C" void kernel_launch(void* const* d_in, const int* in_sizes, int n_in,
                              void* d_out, int out_size, void* d_ws, size_t ws_size,
                              hipStream_t stream) {
    const float* hs   = (const float*)d_in[0];
    const float* ehs  = (const float*)d_in[1];
    const float* bbox = (const float*)d_in[2];
    const float* Wq   = (const float*)d_in[3];
    const float* Wk   = (const float*)d_in[4];
    const float* Wv   = (const float*)d_in[5];
    const float* Wo   = (const float*)d_in[6];
    const float* bo   = (const float*)d_in[7];
    float* out = (float*)d_out;

    float* wPh  = (float*)d_ws;                          // 9*4096
    float* wSum = wPh + (size_t)9 * HW;                  // 4096
    _Float16* hsH  = (_Float16*)(wSum + HW);             // 8192*320
    _Float16* ehsH = hsH + (size_t)2 * HW * C;           // 770*768
    _Float16* WqT  = ehsH + (size_t)NB * L * CX;         // 320*320
    _Float16* WkvT = WqT + (size_t)C * C;                // 640*768
    _Float16* WoT  = WkvT + (size_t)KVC * CX;            // 320*320
    _Float16* Kh   = WoT + (size_t)C * C;                // 800*320
    _Float16* VTg  = Kh + (size_t)800 * C;               // 80*48*96
    _Float16* Xh   = VTg + (size_t)80 * 48 * 96;         // 8192*320

    prep_kernel<<<dim3(NPREP), 256, 0, stream>>>(bbox, hs, ehs, Wq, Wk, Wv, Wo,
                                                 wPh, wSum, hsH, ehsH, WqT, WkvT, WoT,
                                                 VTg, Kh);
    gemm_kv<<<dim3(KVC / 64, (NB * L + 63) / 64), 256, 0, stream>>>(ehsH, WkvT, Kh, VTg);
    attn_mfma<<<dim3(NH * 64), 256, 0, stream>>>(hsH, WqT, Kh, VTg, wPh, Xh);
    gemm_oproj_f16<<<dim3(C / 64, (2 * HW) / 64), 256, 0, stream>>>(Xh, WoT, bo, wSum, out);
}

// Round 10
// 164.670 us; speedup vs baseline: 1.1039x; 1.0141x over previous
//
#include <hip/hip_runtime.h>
#include <math.h>

// Problem constants
#define HW 4096
#define C 320
#define CX 768
#define L 77
#define NB 10
#define NH 8
#define HD 40
#define NINST 8
#define KVC 640
#define SCALE 0.15811388300841898f  // 1/sqrt(40)
#define PSTR 104                    // LDS row stride in halves (2-way banks)

typedef _Float16 half8v __attribute__((ext_vector_type(8)));
typedef _Float16 half4v __attribute__((ext_vector_type(4)));
typedef float f32x4 __attribute__((ext_vector_type(4)));

// prep grid segmentation
#define SEG_MASK   16
#define N_CVT1     (2 * HW * C / 4)
#define N_CVT2     (NB * L * CX / 4)
#define SEG_CVT    (((N_CVT1 + N_CVT2) + 255) / 256)
#define SEG_WPACK  240
#define SEG_VTZ    180                        // 80*48*96/8/256
#define SEG_KPAD   5
#define NPREP      (SEG_MASK + SEG_CVT + SEG_WPACK + SEG_VTZ + SEG_KPAD)

// ---------------------------------------------------------------------------
// prep: maskw + cvt + weight packs + VTg init (zeros + ones-row at d=40)
// + Kh pad-row zeroing, one dispatch.
// ---------------------------------------------------------------------------
__device__ __forceinline__ float axis_profile(int o, float lo, float hi) {
    float num = 0.f, den = 0.f;
    int j0 = 8 * o - 4;
#pragma unroll
    for (int t = 0; t < 16; ++t) {
        int j = j0 + t;
        float wt = 1.0f - fabsf((float)t - 7.5f) * 0.125f;
        if (j >= 0 && j < 512) {
            den += wt;
            float fj = (float)j;
            if (fj >= lo && fj < hi) num += wt;
        }
    }
    return num / den;
}

__global__ __launch_bounds__(256) void prep_kernel(
        const float* __restrict__ bboxes,
        const float* __restrict__ hs, const float* __restrict__ ehs,
        const float* __restrict__ Wq, const float* __restrict__ Wk,
        const float* __restrict__ Wv, const float* __restrict__ Wo,
        float* __restrict__ wPh, float* __restrict__ wSum,
        _Float16* __restrict__ hsH, _Float16* __restrict__ ehsH,
        _Float16* __restrict__ WqT, _Float16* __restrict__ WkvT,
        _Float16* __restrict__ WoT, _Float16* __restrict__ VTg,
        _Float16* __restrict__ Kh) {
    __shared__ float tile[64][65];
    __shared__ float sw_s[NINST][64];
    __shared__ float sh_s[NINST][4];
    int bx = blockIdx.x, tid = threadIdx.x;

    if (bx < SEG_MASK) {
        int oyb = bx * 4;
        for (int i = tid; i < NINST * 64; i += 256) {
            int n = i >> 6, ox = i & 63;
            float lo = floorf(512.f * bboxes[n * 4 + 0]);
            float hi = floorf(512.f * bboxes[n * 4 + 2]);
            sw_s[n][ox] = axis_profile(ox, lo, hi);
        }
        if (tid < NINST * 4) {
            int n = tid >> 2, oy = tid & 3;
            float lo = floorf(512.f * bboxes[n * 4 + 1]);
            float hi = floorf(512.f * bboxes[n * 4 + 3]);
            sh_s[n][oy] = axis_profile(oyb + oy, lo, hi);
        }
        __syncthreads();
        int oy = tid >> 6, ox = tid & 63;
        int hw = (oyb + oy) * 64 + ox;
        float sum = 0.1f;
        wPh[hw] = 0.1f;
#pragma unroll
        for (int n = 0; n < NINST; ++n) {
            float wv = 10.f * sh_s[n][oy] * sw_s[n][ox];
            wPh[(n + 1) * HW + hw] = wv;
            sum += wv;
        }
        wSum[hw] = sum;
    } else if (bx < SEG_MASK + SEG_CVT) {
        int i = (bx - SEG_MASK) * 256 + tid;
        const float* src; _Float16* dst;
        if (i < N_CVT1) { src = hs; dst = hsH; }
        else if (i < N_CVT1 + N_CVT2) { i -= N_CVT1; src = ehs; dst = ehsH; }
        else return;
        float4 v = ((const float4*)src)[i];
        half4v h = {(_Float16)v.x, (_Float16)v.y, (_Float16)v.z, (_Float16)v.w};
        ((half4v*)dst)[i] = h;
    } else if (bx < SEG_MASK + SEG_CVT + SEG_WPACK) {
        int zz = bx - SEG_MASK - SEG_CVT;
        int z = zz / 60, inner = zz - z * 60;
        int by = inner / 5, bx2 = inner - by * 5;
        const float* W; _Float16* WT; int K;
        if (z == 0)      { W = Wq; WT = WqT; K = C; }
        else if (z == 1) { W = Wk; WT = WkvT; K = CX; }
        else if (z == 2) { W = Wv; WT = WkvT + (size_t)C * CX; K = CX; }
        else             { W = Wo; WT = WoT; K = C; }
        int kt = by * 64;
        if (kt >= K) return;
        int nt = bx2 * 64;
#pragma unroll
        for (int p = 0; p < 16; ++p) {
            int idx = p * 256 + tid;
            int k = idx >> 6, n = idx & 63;
            tile[k][n] = W[(size_t)(kt + k) * C + nt + n];
        }
        __syncthreads();
#pragma unroll
        for (int p = 0; p < 16; ++p) {
            int idx = p * 256 + tid;
            int n = idx >> 6, k = idx & 63;
            WT[(size_t)(nt + n) * K + kt + k] = (_Float16)tile[k][n];
        }
    } else if (bx < SEG_MASK + SEG_CVT + SEG_WPACK + SEG_VTZ) {
        // VTg init: zeros; d==40 row = 1.0 for key<77 (ones-row -> PV output
        // row 40 = softmax denominator for free).
        int i = (bx - SEG_MASK - SEG_CVT - SEG_WPACK) * 256 + tid;
        int e0 = i * 8;
        int rem = e0 % (48 * 96);
        int d = rem / 96;
        int key0 = rem % 96;
        half8v v;
#pragma unroll
        for (int j = 0; j < 8; ++j)
            v[j] = (_Float16)((d == 40 && (key0 + j) < 77) ? 1.f : 0.f);
        ((half8v*)VTg)[i] = v;
    } else {
        // Kh pad rows (key 77..79) = 0 -> score 0 -> p=1, nullified by V/ones zeros.
        int i = (bx - SEG_MASK - SEG_CVT - SEG_WPACK - SEG_VTZ) * 256 + tid;
        if (i < 1200) {
            int rowIdx = i / 40, c8 = i - rowIdx * 40;
            int b = rowIdx / 3, k = 77 + rowIdx - (rowIdx / 3) * 3;
            half8v z8 = {(_Float16)0.f,(_Float16)0.f,(_Float16)0.f,(_Float16)0.f,
                         (_Float16)0.f,(_Float16)0.f,(_Float16)0.f,(_Float16)0.f};
            ((half8v*)(Kh + (size_t)(b * 80 + k) * C))[c8] = z8;
        }
    }
}

// ---------------------------------------------------------------------------
// K/V projection. K half -> Kh(800,320); V half -> directly transposed VTg.
// ---------------------------------------------------------------------------
__global__ __launch_bounds__(256) void gemm_kv(const _Float16* __restrict__ A,
                                               const _Float16* __restrict__ BT,
                                               _Float16* __restrict__ Kh,
                                               _Float16* __restrict__ VTg) {
    const int K = CX, M = NB * L;
    int lane = threadIdx.x & 63, wave = threadIdx.x >> 6;
    int m0 = blockIdx.y * 64 + wave * 16;
    int n0 = blockIdx.x * 64;
    int lr = lane & 15, kq = (lane >> 4) * 8;
    int arow = m0 + lr; if (arow >= M) arow = M - 1;
    const _Float16* ap = A + (size_t)arow * K + kq;
    const _Float16* bp = BT + (size_t)(n0 + lr) * K + kq;
    f32x4 acc0 = {0.f,0.f,0.f,0.f}, acc1 = acc0, acc2 = acc0, acc3 = acc0;
    for (int k0 = 0; k0 < K; k0 += 32) {
        half8v af = *(const half8v*)(ap + k0);
        half8v b0 = *(const half8v*)(bp + k0);
        half8v b1 = *(const half8v*)(bp + (size_t)16 * K + k0);
        half8v b2 = *(const half8v*)(bp + (size_t)32 * K + k0);
        half8v b3 = *(const half8v*)(bp + (size_t)48 * K + k0);
        acc0 = __builtin_amdgcn_mfma_f32_16x16x32_f16(af, b0, acc0, 0, 0, 0);
        acc1 = __builtin_amdgcn_mfma_f32_16x16x32_f16(af, b1, acc1, 0, 0, 0);
        acc2 = __builtin_amdgcn_mfma_f32_16x16x32_f16(af, b2, acc2, 0, 0, 0);
        acc3 = __builtin_amdgcn_mfma_f32_16x16x32_f16(af, b3, acc3, 0, 0, 0);
    }
    int rb = m0 + ((lane >> 4) << 2);
    f32x4 accs[4] = {acc0, acc1, acc2, acc3};
#pragma unroll
    for (int t = 0; t < 4; ++t) {
        int col = n0 + t * 16 + lr;
#pragma unroll
        for (int r = 0; r < 4; ++r) {
            int row = rb + r;
            if (row < M) {
                int bb = row / 77;
                int key = row - bb * 77;
                if (col < C) {
                    Kh[(size_t)(bb * 80 + key) * C + col] = (_Float16)accs[t][r];
                } else {
                    int ch = col - C;
                    int h = ch / HD;
                    int d = ch - h * HD;
                    VTg[((size_t)(bb * 8 + h) * 48 + d) * 96 + key] = (_Float16)accs[t][r];
                }
            }
        }
    }
}

// ---------------------------------------------------------------------------
// MFMA attention, transposed dataflow + SOFTWARE-PIPELINED pair loop.
// r9 post-mortem: all pipes idle, VGPR=56 -> compiler issued the 38 global
// fragment loads per pair right before use (zero prefetch distance); the
// kernel was pure load-latency. Fix: fully-unrolled pair loop with explicit
// prefetch: pair-0 K/V load before phase 1; pair p+1's K loads issue after
// p's QK MFMAs, V loads after p's PV; wPh loads at body top.
// ---------------------------------------------------------------------------
__global__ __launch_bounds__(256, 2) void attn_mfma(const _Float16* __restrict__ hsH,  // (8192,320)
                                                    const _Float16* __restrict__ WqT,  // (320,320)
                                                    const _Float16* __restrict__ Kh,   // (800,320)
                                                    const _Float16* __restrict__ VTg,  // (80,48,96)
                                                    const float* __restrict__ wPh,     // (9,HW)
                                                    _Float16* __restrict__ Xh) {       // (8192,320)
    __shared__ _Float16 plds[4][2][16 * PSTR];
    int wave = threadIdx.x >> 6, lane = threadIdx.x & 63;
    int head = blockIdx.x >> 6;
    int qg = blockIdx.x & 63;
    int qrow0 = qg * 64 + wave * 16;
    int c = lane & 15, quad = lane >> 4;
    _Float16* pl0 = &plds[wave][0][0];
    _Float16* pl1 = &plds[wave][1][0];
    half8v zero8 = {(_Float16)0.f,(_Float16)0.f,(_Float16)0.f,(_Float16)0.f,
                    (_Float16)0.f,(_Float16)0.f,(_Float16)0.f,(_Float16)0.f};

    const _Float16* kbase = Kh + (size_t)c * C + head * HD + quad * 8;
    const _Float16* vbase = VTg + ((size_t)head * 48 + c) * 96 + quad * 8;

    // prologue: zero halves [row][40..95] in both buffers
#pragma unroll
    for (int i = 0; i < 4; ++i) {
        int idx = i * 64 + lane;
        if (idx < 224) {
            int buf = idx / 112;
            int rem = idx - buf * 112;
            int row = rem / 7, ch = rem - row * 7;
            *(half8v*)&plds[wave][buf][row * PSTR + 40 + ch * 8] = zero8;
        }
    }

    // ---- prefetch pair 0 K/V fragments (overlaps phase-1 compute) ----
    half8v kxa[5], kxb[5], kya[5], kyb[5];
#pragma unroll
    for (int u = 0; u < 5; ++u) {
        const _Float16* kx = kbase + (size_t)u * 16 * C;
        const _Float16* ky = kx + (size_t)80 * C;
        kxa[u] = *(const half8v*)(kx);
        kxb[u] = *(const half8v*)(kx + 32);
        kya[u] = *(const half8v*)(ky);
        kyb[u] = *(const half8v*)(ky + 32);
    }
    half8v vx[9], vy[9];
#pragma unroll
    for (int t = 0; t < 3; ++t) {
#pragma unroll
        for (int s = 0; s < 3; ++s) {
            const _Float16* vxp = vbase + (size_t)t * 16 * 96 + s * 32;
            vx[t * 3 + s] = *(const half8v*)(vxp);
            vy[t * 3 + s] = *(const half8v*)(vxp + (size_t)8 * 48 * 96);
        }
    }

    // ---- Phase 1: Q^T projection: A=WqT rows (d), B=hs rows (qrow) ----
    {
        const _Float16* bu = hsH + (size_t)(qrow0 + c) * C + quad * 8;
        const _Float16* bc = bu + (size_t)HW * C;
        f32x4 qa0[3] = {}, qa1[3] = {};
        for (int k0 = 0; k0 < C; k0 += 32) {
            half8v hu = *(const half8v*)(bu + k0);
            half8v hc = *(const half8v*)(bc + k0);
#pragma unroll
            for (int t = 0; t < 3; ++t) {
                const _Float16* ap = WqT + (size_t)(head * HD + t * 16 + c) * C + quad * 8 + k0;
                half8v af = *(const half8v*)ap;
                qa0[t] = __builtin_amdgcn_mfma_f32_16x16x32_f16(af, hu, qa0[t], 0, 0, 0);
                qa1[t] = __builtin_amdgcn_mfma_f32_16x16x32_f16(af, hc, qa1[t], 0, 0, 0);
            }
        }
#pragma unroll
        for (int t = 0; t < 3; ++t) {
            if (t < 2 || quad < 2) {
                half4v h0 = {(_Float16)(qa0[t][0] * SCALE), (_Float16)(qa0[t][1] * SCALE),
                             (_Float16)(qa0[t][2] * SCALE), (_Float16)(qa0[t][3] * SCALE)};
                half4v h1 = {(_Float16)(qa1[t][0] * SCALE), (_Float16)(qa1[t][1] * SCALE),
                             (_Float16)(qa1[t][2] * SCALE), (_Float16)(qa1[t][3] * SCALE)};
                *(half4v*)(pl0 + c * PSTR + t * 16 + quad * 4) = h0;
                *(half4v*)(pl1 + c * PSTR + t * 16 + quad * 4) = h1;
            }
        }
    }
    // intra-wave LDS RAW: in-order DS pipe + compiler waitcnt (r5-r9 verified)
    half8v qu0 = *(const half8v*)(pl0 + (size_t)c * PSTR + quad * 8);
    half8v qu1 = *(const half8v*)(pl0 + (size_t)c * PSTR + 32 + quad * 8);
    half8v qc0 = *(const half8v*)(pl1 + (size_t)c * PSTR + quad * 8);
    half8v qc1 = *(const half8v*)(pl1 + (size_t)c * PSTR + 32 + quad * 8);

    f32x4 oacc[3] = {};
    int srcl = 32 + c;   // lane holding O^T row d=40 (denominator) for qrow c

    // ---- Phase 2: pipelined batch pairs (0,1),(2,3),(4,5),(6,7),(8,9) ----
#pragma unroll
    for (int p = 0; p < 5; ++p) {
        int bx = 2 * p, by = bx + 1;
        half8v ax0 = p ? qc0 : qu0;
        half8v ax1 = p ? qc1 : qu1;

        // phase-weight loads early (latency hidden behind QK/exp)
        float wx = (p == 0) ? 1.f : wPh[(size_t)(bx - 1) * HW + qrow0 + c];
        float wy = wPh[(size_t)(by - 1) * HW + qrow0 + c];

        // QK^T: A=K rows (key), B=Q -> S^T col=qrow, rows=keys
        f32x4 sx[5], sy[5];
#pragma unroll
        for (int u = 0; u < 5; ++u) {
            f32x4 a = {0.f,0.f,0.f,0.f};
            a = __builtin_amdgcn_mfma_f32_16x16x32_f16(kxa[u], ax0, a, 0, 0, 0);
            a = __builtin_amdgcn_mfma_f32_16x16x32_f16(kxb[u], ax1, a, 0, 0, 0);
            sx[u] = a;
            f32x4 b = {0.f,0.f,0.f,0.f};
            b = __builtin_amdgcn_mfma_f32_16x16x32_f16(kya[u], qc0, b, 0, 0, 0);
            b = __builtin_amdgcn_mfma_f32_16x16x32_f16(kyb[u], qc1, b, 0, 0, 0);
            sy[u] = b;
        }

        // ---- prefetch next pair's K (consumed next iteration) ----
        if (p < 4) {
            const _Float16* kxn = kbase + (size_t)(bx + 2) * 80 * C;
#pragma unroll
            for (int u = 0; u < 5; ++u) {
                const _Float16* kx = kxn + (size_t)u * 16 * C;
                const _Float16* ky = kx + (size_t)80 * C;
                kxa[u] = *(const half8v*)(kx);
                kxb[u] = *(const half8v*)(kx + 32);
                kya[u] = *(const half8v*)(ky);
                kyb[u] = *(const half8v*)(ky + 32);
            }
        }

        // exp (scale pre-folded) + P^T -> LDS
#pragma unroll
        for (int u = 0; u < 5; ++u) {
            half4v hx = {(_Float16)__expf(sx[u][0]), (_Float16)__expf(sx[u][1]),
                         (_Float16)__expf(sx[u][2]), (_Float16)__expf(sx[u][3])};
            half4v hy = {(_Float16)__expf(sy[u][0]), (_Float16)__expf(sy[u][1]),
                         (_Float16)__expf(sy[u][2]), (_Float16)__expf(sy[u][3])};
            *(half4v*)(pl0 + c * PSTR + u * 16 + quad * 4) = hx;
            *(half4v*)(pl1 + c * PSTR + u * 16 + quad * 4) = hy;
        }

        // P^T B-fragments
        half8v px0 = *(const half8v*)(pl0 + (size_t)c * PSTR + 0  + quad * 8);
        half8v px1 = *(const half8v*)(pl0 + (size_t)c * PSTR + 32 + quad * 8);
        half8v px2 = *(const half8v*)(pl0 + (size_t)c * PSTR + 64 + quad * 8);
        half8v py0 = *(const half8v*)(pl1 + (size_t)c * PSTR + 0  + quad * 8);
        half8v py1 = *(const half8v*)(pl1 + (size_t)c * PSTR + 32 + quad * 8);
        half8v py2 = *(const half8v*)(pl1 + (size_t)c * PSTR + 64 + quad * 8);

        // PV: A=V^T rows (d), B=P^T -> O^T col=qrow, rows=d
        f32x4 ox[3], oy[3];
#pragma unroll
        for (int t = 0; t < 3; ++t) {
            f32x4 a = {0.f,0.f,0.f,0.f};
            a = __builtin_amdgcn_mfma_f32_16x16x32_f16(vx[t*3+0], px0, a, 0, 0, 0);
            a = __builtin_amdgcn_mfma_f32_16x16x32_f16(vx[t*3+1], px1, a, 0, 0, 0);
            a = __builtin_amdgcn_mfma_f32_16x16x32_f16(vx[t*3+2], px2, a, 0, 0, 0);
            ox[t] = a;
            f32x4 b = {0.f,0.f,0.f,0.f};
            b = __builtin_amdgcn_mfma_f32_16x16x32_f16(vy[t*3+0], py0, b, 0, 0, 0);
            b = __builtin_amdgcn_mfma_f32_16x16x32_f16(vy[t*3+1], py1, b, 0, 0, 0);
            b = __builtin_amdgcn_mfma_f32_16x16x32_f16(vy[t*3+2], py2, b, 0, 0, 0);
            oy[t] = b;
        }

        // ---- prefetch next pair's V ----
        if (p < 4) {
            const _Float16* vxn = vbase + (size_t)(bx + 2) * 8 * 48 * 96;
#pragma unroll
            for (int t = 0; t < 3; ++t) {
#pragma unroll
                for (int s = 0; s < 3; ++s) {
                    const _Float16* vp = vxn + (size_t)t * 16 * 96 + s * 32;
                    vx[t * 3 + s] = *(const half8v*)(vp);
                    vy[t * 3 + s] = *(const half8v*)(vp + (size_t)8 * 48 * 96);
                }
            }
        }

        // denominators: O^T row d=40 = tile2 reg0 at quad 2 -> one shfl each
        float lx = __shfl(ox[2][0], srcl, 64);
        float ly = __shfl(oy[2][0], srcl, 64);

        if (p == 0) {
            float rin = 1.0f / lx;
#pragma unroll
            for (int t = 0; t < 3; ++t) {
                if (t < 2 || quad < 2) {
                    half4v h = {(_Float16)(ox[t][0] * rin), (_Float16)(ox[t][1] * rin),
                                (_Float16)(ox[t][2] * rin), (_Float16)(ox[t][3] * rin)};
                    *(half4v*)(Xh + (size_t)(qrow0 + c) * C + head * HD + t * 16 + quad * 4) = h;
                }
            }
        } else {
            float rfx = wx / lx;
#pragma unroll
            for (int t = 0; t < 3; ++t) {
                oacc[t][0] += ox[t][0] * rfx;
                oacc[t][1] += ox[t][1] * rfx;
                oacc[t][2] += ox[t][2] * rfx;
                oacc[t][3] += ox[t][3] * rfx;
            }
        }
        {
            float rfy = wy / ly;
#pragma unroll
            for (int t = 0; t < 3; ++t) {
                oacc[t][0] += oy[t][0] * rfy;
                oacc[t][1] += oy[t][1] * rfy;
                oacc[t][2] += oy[t][2] * rfy;
                oacc[t][3] += oy[t][3] * rfy;
            }
        }
    }

    // write fused cond rows (8B vector stores)
#pragma unroll
    for (int t = 0; t < 3; ++t) {
        if (t < 2 || quad < 2) {
            half4v h = {(_Float16)oacc[t][0], (_Float16)oacc[t][1],
                        (_Float16)oacc[t][2], (_Float16)oacc[t][3]};
            *(half4v*)(Xh + (size_t)(HW + qrow0 + c) * C + head * HD + t * 16 + quad * 4) = h;
        }
    }
}

// ---------------------------------------------------------------------------
// O-projection f16 MFMA GEMM with fused epilogue.
// ---------------------------------------------------------------------------
__global__ __launch_bounds__(256) void gemm_oproj_f16(const _Float16* __restrict__ A,
                                                      const _Float16* __restrict__ BT,
                                                      const float* __restrict__ bo,
                                                      const float* __restrict__ wSum,
                                                      float* __restrict__ Out) {
    const int K = C;
    int lane = threadIdx.x & 63, wave = threadIdx.x >> 6;
    int m0 = blockIdx.y * 64 + wave * 16;
    int n0 = blockIdx.x * 64;
    int lr = lane & 15, kq = (lane >> 4) * 8;
    const _Float16* ap = A + (size_t)(m0 + lr) * K + kq;
    const _Float16* bp = BT + (size_t)(n0 + lr) * K + kq;
    f32x4 acc0 = {0.f,0.f,0.f,0.f}, acc1 = acc0, acc2 = acc0, acc3 = acc0;
    for (int k0 = 0; k0 < K; k0 += 32) {
        half8v af = *(const half8v*)(ap + k0);
        half8v b0 = *(const half8v*)(bp + k0);
        half8v b1 = *(const half8v*)(bp + (size_t)16 * K + k0);
        half8v b2 = *(const half8v*)(bp + (size_t)32 * K + k0);
        half8v b3 = *(const half8v*)(bp + (size_t)48 * K + k0);
        acc0 = __builtin_amdgcn_mfma_f32_16x16x32_f16(af, b0, acc0, 0, 0, 0);
        acc1 = __builtin_amdgcn_mfma_f32_16x16x32_f16(af, b1, acc1, 0, 0, 0);
        acc2 = __builtin_amdgcn_mfma_f32_16x16x32_f16(af, b2, acc2, 0, 0, 0);
        acc3 = __builtin_amdgcn_mfma_f32_16x16x32_f16(af, b3, acc3, 0, 0, 0);
    }
    int rb = m0 + ((lane >> 4) << 2);
    f32x4 accs[4] = {acc0, acc1, acc2, acc3};
#pragma unroll
    for (int t = 0; t < 4; ++t) {
        int col = n0 + t * 16 + lr;
        float bv = bo[col];
#pragma unroll
        for (int r = 0; r < 4; ++r) {
            int row = rb + r;
            float v = accs[t][r];
            if (row < HW) {
                v += bv;
            } else {
                float ws = wSum[row - HW];
                v = (v + bv * ws) / (ws + 1e-6f);
            }
            Out[(size_t)row * C + col] = v;
        }
    }
}

// ---------------------------------------------------------------------------
// Launch: 4 dispatches.
// ---------------------------------------------------------------------------
extern "C" void kernel_launch(void* const* d_in, const int* in_sizes, int n_in,
                              void* d_out, int out_size, void* d_ws, size_t ws_size,
                              hipStream_t stream) {
    const float* hs   = (const float*)d_in[0];
    const float* ehs  = (const float*)d_in[1];
    const float* bbox = (const float*)d_in[2];
    const float* Wq   = (const float*)d_in[3];
    const float* Wk   = (const float*)d_in[4];
    const float* Wv   = (const float*)d_in[5];
    const float* Wo   = (const float*)d_in[6];
    const float* bo   = (const float*)d_in[7];
    float* out = (float*)d_out;

    float* wPh  = (float*)d_ws;                          // 9*4096
    float* wSum = wPh + (size_t)9 * HW;                  // 4096
    _Float16* hsH  = (_Float16*)(wSum + HW);             // 8192*320
    _Float16* ehsH = hsH + (size_t)2 * HW * C;           // 770*768
    _Float16* WqT  = ehsH + (size_t)NB * L * CX;         // 320*320
    _Float16* WkvT = WqT + (size_t)C * C;                // 640*768
    _Float16* WoT  = WkvT + (size_t)KVC * CX;            // 320*320
    _Float16* Kh   = WoT + (size_t)C * C;                // 800*320
    _Float16* VTg  = Kh + (size_t)800 * C;               // 80*48*96
    _Float16* Xh   = VTg + (size_t)80 * 48 * 96;         // 8192*320

    prep_kernel<<<dim3(NPREP), 256, 0, stream>>>(bbox, hs, ehs, Wq, Wk, Wv, Wo,
                                                 wPh, wSum, hsH, ehsH, WqT, WkvT, WoT,
                                                 VTg, Kh);
    gemm_kv<<<dim3(KVC / 64, (NB * L + 63) / 64), 256, 0, stream>>>(ehsH, WkvT, Kh, VTg);
    attn_mfma<<<dim3(NH * 64), 256, 0, stream>>>(hsH, WqT, Kh, VTg, wPh, Xh);
    gemm_oproj_f16<<<dim3(C / 64, (2 * HW) / 64), 256, 0, stream>>>(Xh, WoT, bo, wSum, out);
}

// Round 11
// 132.302 us; speedup vs baseline: 1.3739x; 1.2447x over previous
//
#include <hip/hip_runtime.h>
#include <math.h>

// Problem constants
#define HW 4096
#define C 320
#define CX 768
#define L 77
#define NB 10
#define NH 8
#define HD 40
#define NINST 8
#define KVC 640
#define SCALE 0.15811388300841898f  // 1/sqrt(40)
#define PSTR 104                    // P LDS row stride in halves
#define KSTR 48                     // staged K row stride (halves, 16B-aligned)
#define VSTR 104                    // staged V row stride (halves, 16B-aligned)

typedef _Float16 half8v __attribute__((ext_vector_type(8)));
typedef _Float16 half4v __attribute__((ext_vector_type(4)));
typedef float f32x4 __attribute__((ext_vector_type(4)));

// per-(b,h) packed sizes in halves
#define KBH (80 * KSTR)             // 3840
#define VBH (48 * VSTR)             // 4992

// prep grid segmentation
#define SEG_MASK   16
#define N_CVT1     (2 * HW * C / 4)
#define N_CVT2     (NB * L * CX / 4)
#define SEG_CVT    (((N_CVT1 + N_CVT2) + 255) / 256)  // 3138
#define SEG_WPACK  240
#define SEG_VTZ    195                 // 80*VBH/8/256 = 49920/256
#define SEG_KPAD   6                   // 80*3*KSTR/8 = 1440 chunks
#define NPREP      (SEG_MASK + SEG_CVT + SEG_WPACK + SEG_VTZ + SEG_KPAD)

// ---------------------------------------------------------------------------
// prep: maskw + cvt + weight packs + VTg init (zeros + ones-row at d=40)
// + Khp pad-key-row zeroing, one dispatch.
// ---------------------------------------------------------------------------
__device__ __forceinline__ float axis_profile(int o, float lo, float hi) {
    float num = 0.f, den = 0.f;
    int j0 = 8 * o - 4;
#pragma unroll
    for (int t = 0; t < 16; ++t) {
        int j = j0 + t;
        float wt = 1.0f - fabsf((float)t - 7.5f) * 0.125f;
        if (j >= 0 && j < 512) {
            den += wt;
            float fj = (float)j;
            if (fj >= lo && fj < hi) num += wt;
        }
    }
    return num / den;
}

__global__ __launch_bounds__(256) void prep_kernel(
        const float* __restrict__ bboxes,
        const float* __restrict__ hs, const float* __restrict__ ehs,
        const float* __restrict__ Wq, const float* __restrict__ Wk,
        const float* __restrict__ Wv, const float* __restrict__ Wo,
        float* __restrict__ wPh, float* __restrict__ wSum,
        _Float16* __restrict__ hsH, _Float16* __restrict__ ehsH,
        _Float16* __restrict__ WqT, _Float16* __restrict__ WkvT,
        _Float16* __restrict__ WoT, _Float16* __restrict__ VTg,
        _Float16* __restrict__ Khp) {
    __shared__ float tile[64][65];
    __shared__ float sw_s[NINST][64];
    __shared__ float sh_s[NINST][4];
    int bx = blockIdx.x, tid = threadIdx.x;

    if (bx < SEG_MASK) {
        int oyb = bx * 4;
        for (int i = tid; i < NINST * 64; i += 256) {
            int n = i >> 6, ox = i & 63;
            float lo = floorf(512.f * bboxes[n * 4 + 0]);
            float hi = floorf(512.f * bboxes[n * 4 + 2]);
            sw_s[n][ox] = axis_profile(ox, lo, hi);
        }
        if (tid < NINST * 4) {
            int n = tid >> 2, oy = tid & 3;
            float lo = floorf(512.f * bboxes[n * 4 + 1]);
            float hi = floorf(512.f * bboxes[n * 4 + 3]);
            sh_s[n][oy] = axis_profile(oyb + oy, lo, hi);
        }
        __syncthreads();
        int oy = tid >> 6, ox = tid & 63;
        int hw = (oyb + oy) * 64 + ox;
        float sum = 0.1f;
        wPh[hw] = 0.1f;
#pragma unroll
        for (int n = 0; n < NINST; ++n) {
            float wv = 10.f * sh_s[n][oy] * sw_s[n][ox];
            wPh[(n + 1) * HW + hw] = wv;
            sum += wv;
        }
        wSum[hw] = sum;
    } else if (bx < SEG_MASK + SEG_CVT) {
        int i = (bx - SEG_MASK) * 256 + tid;
        const float* src; _Float16* dst;
        if (i < N_CVT1) { src = hs; dst = hsH; }
        else if (i < N_CVT1 + N_CVT2) { i -= N_CVT1; src = ehs; dst = ehsH; }
        else return;
        float4 v = ((const float4*)src)[i];
        half4v h = {(_Float16)v.x, (_Float16)v.y, (_Float16)v.z, (_Float16)v.w};
        ((half4v*)dst)[i] = h;
    } else if (bx < SEG_MASK + SEG_CVT + SEG_WPACK) {
        int zz = bx - SEG_MASK - SEG_CVT;
        int z = zz / 60, inner = zz - z * 60;
        int by = inner / 5, bx2 = inner - by * 5;
        const float* W; _Float16* WT; int K;
        if (z == 0)      { W = Wq; WT = WqT; K = C; }
        else if (z == 1) { W = Wk; WT = WkvT; K = CX; }
        else if (z == 2) { W = Wv; WT = WkvT + (size_t)C * CX; K = CX; }
        else             { W = Wo; WT = WoT; K = C; }
        int kt = by * 64;
        if (kt >= K) return;
        int nt = bx2 * 64;
#pragma unroll
        for (int p = 0; p < 16; ++p) {
            int idx = p * 256 + tid;
            int k = idx >> 6, n = idx & 63;
            tile[k][n] = W[(size_t)(kt + k) * C + nt + n];
        }
        __syncthreads();
#pragma unroll
        for (int p = 0; p < 16; ++p) {
            int idx = p * 256 + tid;
            int n = idx >> 6, k = idx & 63;
            WT[(size_t)(nt + n) * K + kt + k] = (_Float16)tile[k][n];
        }
    } else if (bx < SEG_MASK + SEG_CVT + SEG_WPACK + SEG_VTZ) {
        // VTg init (stride VSTR): zeros; d==40 row = 1.0 for key<77
        int i = (bx - SEG_MASK - SEG_CVT - SEG_WPACK) * 256 + tid;  // half8 idx
        int e0 = i * 8;
        int rem = e0 % VBH;
        int d = rem / VSTR;
        int key0 = rem % VSTR;
        half8v v;
#pragma unroll
        for (int j = 0; j < 8; ++j)
            v[j] = (_Float16)((d == 40 && (key0 + j) < 77) ? 1.f : 0.f);
        ((half8v*)VTg)[i] = v;
    } else {
        // Khp pad key rows 77..79 per (b,h) = 0
        int i = (bx - SEG_MASK - SEG_CVT - SEG_WPACK - SEG_VTZ) * 256 + tid;
        if (i < 1440) {
            int rowIdx = i / 6, c8 = i - rowIdx * 6;   // 6 half8 per KSTR row
            int bh = rowIdx / 3;
            int key = 77 + rowIdx - bh * 3;
            half8v z8 = {(_Float16)0.f,(_Float16)0.f,(_Float16)0.f,(_Float16)0.f,
                         (_Float16)0.f,(_Float16)0.f,(_Float16)0.f,(_Float16)0.f};
            *(half8v*)(Khp + ((size_t)bh * 80 + key) * KSTR + c8 * 8) = z8;
        }
    }
}

// ---------------------------------------------------------------------------
// K/V projection. K half -> Khp[b][h][key][KSTR] packed per (b,head);
// V half -> VTg[b][h][d][VSTR] transposed. Both f16 scatter stores.
// ---------------------------------------------------------------------------
__global__ __launch_bounds__(256) void gemm_kv(const _Float16* __restrict__ A,
                                               const _Float16* __restrict__ BT,
                                               _Float16* __restrict__ Khp,
                                               _Float16* __restrict__ VTg) {
    const int K = CX, M = NB * L;
    int lane = threadIdx.x & 63, wave = threadIdx.x >> 6;
    int m0 = blockIdx.y * 64 + wave * 16;
    int n0 = blockIdx.x * 64;
    int lr = lane & 15, kq = (lane >> 4) * 8;
    int arow = m0 + lr; if (arow >= M) arow = M - 1;
    const _Float16* ap = A + (size_t)arow * K + kq;
    const _Float16* bp = BT + (size_t)(n0 + lr) * K + kq;
    f32x4 acc0 = {0.f,0.f,0.f,0.f}, acc1 = acc0, acc2 = acc0, acc3 = acc0;
    for (int k0 = 0; k0 < K; k0 += 32) {
        half8v af = *(const half8v*)(ap + k0);
        half8v b0 = *(const half8v*)(bp + k0);
        half8v b1 = *(const half8v*)(bp + (size_t)16 * K + k0);
        half8v b2 = *(const half8v*)(bp + (size_t)32 * K + k0);
        half8v b3 = *(const half8v*)(bp + (size_t)48 * K + k0);
        acc0 = __builtin_amdgcn_mfma_f32_16x16x32_f16(af, b0, acc0, 0, 0, 0);
        acc1 = __builtin_amdgcn_mfma_f32_16x16x32_f16(af, b1, acc1, 0, 0, 0);
        acc2 = __builtin_amdgcn_mfma_f32_16x16x32_f16(af, b2, acc2, 0, 0, 0);
        acc3 = __builtin_amdgcn_mfma_f32_16x16x32_f16(af, b3, acc3, 0, 0, 0);
    }
    int rb = m0 + ((lane >> 4) << 2);
    f32x4 accs[4] = {acc0, acc1, acc2, acc3};
#pragma unroll
    for (int t = 0; t < 4; ++t) {
        int col = n0 + t * 16 + lr;
#pragma unroll
        for (int r = 0; r < 4; ++r) {
            int row = rb + r;
            if (row < M) {
                int bb = row / 77;
                int key = row - bb * 77;
                if (col < C) {
                    int h = col / HD, d = col - h * HD;
                    Khp[((size_t)(bb * 8 + h) * 80 + key) * KSTR + d] = (_Float16)accs[t][r];
                } else {
                    int ch = col - C;
                    int h = ch / HD, d = ch - h * HD;
                    VTg[((size_t)(bb * 8 + h) * 48 + d) * VSTR + key] = (_Float16)accs[t][r];
                }
            }
        }
    }
}

// ---------------------------------------------------------------------------
// MFMA attention v6: transposed dataflow + block-level double-buffered LDS
// staging of K/V (r10 post-mortem: VGPR-held prefetch was serialized by the
// register allocator; LDS is the right storage class, and the 4 waves per
// block no longer each load identical fragments -> 4x less L2 traffic).
// Loop: issue global loads for batch b+1 -> compute b from LDS -> write
// b+1 to the other buffer -> barrier.
// ---------------------------------------------------------------------------
__global__ __launch_bounds__(256, 2) void attn_mfma(const _Float16* __restrict__ hsH,  // (8192,320)
                                                    const _Float16* __restrict__ WqT,  // (320,320)
                                                    const _Float16* __restrict__ Khp,  // (80,80,KSTR)
                                                    const _Float16* __restrict__ VTg,  // (80,48,VSTR)
                                                    const float* __restrict__ wPh,     // (9,HW)
                                                    _Float16* __restrict__ Xh) {       // (8192,320)
    // [ K0 | V0 | K1 | V1 | P-bufs ] ; K overflow reads (nullified garbage)
    // land in the adjacent V region -> keep this order.
    __shared__ _Float16 smem[2 * (KBH + VBH) + 4 * 2 * 16 * PSTR];
    _Float16* Ks0 = smem;
    _Float16* Vs0 = smem + KBH;
    _Float16* Ks1 = smem + KBH + VBH;
    _Float16* Vs1 = smem + 2 * KBH + VBH;
    _Float16* pbase = smem + 2 * (KBH + VBH);

    int tid = threadIdx.x;
    int wave = tid >> 6, lane = tid & 63;
    int head = blockIdx.x >> 6;
    int qg = blockIdx.x & 63;
    int qrow0 = qg * 64 + wave * 16;
    int c = lane & 15, quad = lane >> 4;
    _Float16* pl0 = pbase + (size_t)(wave * 2) * 16 * PSTR;
    _Float16* pl1 = pl0 + 16 * PSTR;
    half8v zero8 = {(_Float16)0.f,(_Float16)0.f,(_Float16)0.f,(_Float16)0.f,
                    (_Float16)0.f,(_Float16)0.f,(_Float16)0.f,(_Float16)0.f};

    const half8v* Kg8 = (const half8v*)(Khp + (size_t)head * KBH);
    const half8v* Vg8 = (const half8v*)(VTg + (size_t)head * VBH);
    const size_t kstep = (size_t)8 * KBH / 8;   // half8 chunks per batch step
    const size_t vstep = (size_t)8 * VBH / 8;

    // issue batch-0 stage loads (consumed after phase 1)
    half8v kr0, kr1, vr0, vr1, vr2;
    kr0 = Kg8[tid];
    if (tid < 224) kr1 = Kg8[tid + 256];
    vr0 = Vg8[tid];
    vr1 = Vg8[tid + 256];
    if (tid < 112) vr2 = Vg8[tid + 512];

    // zero P-buf cols 40..95 (Q pad + P pad keys 80..95)
#pragma unroll
    for (int i = 0; i < 4; ++i) {
        int idx = i * 64 + lane;
        if (idx < 224) {
            int buf = idx / 112;
            int rem = idx - buf * 112;
            int row = rem / 7, ch = rem - row * 7;
            _Float16* pb = buf ? pl1 : pl0;
            *(half8v*)&pb[row * PSTR + 40 + ch * 8] = zero8;
        }
    }

    // ---- Phase 1: Q^T projection (A=WqT rows d, B=hs rows qrow), SCALE folded ----
    {
        const _Float16* bu = hsH + (size_t)(qrow0 + c) * C + quad * 8;
        const _Float16* bc = bu + (size_t)HW * C;
        f32x4 qa0[3] = {}, qa1[3] = {};
        for (int k0 = 0; k0 < C; k0 += 32) {
            half8v hu = *(const half8v*)(bu + k0);
            half8v hc = *(const half8v*)(bc + k0);
#pragma unroll
            for (int t = 0; t < 3; ++t) {
                const _Float16* ap = WqT + (size_t)(head * HD + t * 16 + c) * C + quad * 8 + k0;
                half8v af = *(const half8v*)ap;
                qa0[t] = __builtin_amdgcn_mfma_f32_16x16x32_f16(af, hu, qa0[t], 0, 0, 0);
                qa1[t] = __builtin_amdgcn_mfma_f32_16x16x32_f16(af, hc, qa1[t], 0, 0, 0);
            }
        }
#pragma unroll
        for (int t = 0; t < 3; ++t) {
            if (t < 2 || quad < 2) {
                half4v h0 = {(_Float16)(qa0[t][0] * SCALE), (_Float16)(qa0[t][1] * SCALE),
                             (_Float16)(qa0[t][2] * SCALE), (_Float16)(qa0[t][3] * SCALE)};
                half4v h1 = {(_Float16)(qa1[t][0] * SCALE), (_Float16)(qa1[t][1] * SCALE),
                             (_Float16)(qa1[t][2] * SCALE), (_Float16)(qa1[t][3] * SCALE)};
                *(half4v*)(pl0 + c * PSTR + t * 16 + quad * 4) = h0;
                *(half4v*)(pl1 + c * PSTR + t * 16 + quad * 4) = h1;
            }
        }
    }
    // intra-wave LDS RAW: in-order DS pipe + compiler waitcnt (r5-r10 verified)
    half8v qu0 = *(const half8v*)(pl0 + (size_t)c * PSTR + quad * 8);
    half8v qu1 = *(const half8v*)(pl0 + (size_t)c * PSTR + 32 + quad * 8);
    half8v qc0 = *(const half8v*)(pl1 + (size_t)c * PSTR + quad * 8);
    half8v qc1 = *(const half8v*)(pl1 + (size_t)c * PSTR + 32 + quad * 8);

    // write staged batch-0 into buffer 0
    {
        half8v* Kd = (half8v*)Ks0;
        half8v* Vd = (half8v*)Vs0;
        Kd[tid] = kr0;
        if (tid < 224) Kd[tid + 256] = kr1;
        Vd[tid] = vr0;
        Vd[tid + 256] = vr1;
        if (tid < 112) Vd[tid + 512] = vr2;
    }
    __syncthreads();

    f32x4 oacc[3] = {};
    int srcl = 32 + c;   // lane holding O^T row d=40 (denominator) for qrow c

    for (int b = 0; b < NB; ++b) {
        // ---- issue next batch's stage loads ----
        if (b + 1 < NB) {
            const half8v* Kn = Kg8 + (size_t)(b + 1) * 8 * (KBH / 8);
            const half8v* Vn = Vg8 + (size_t)(b + 1) * 8 * (VBH / 8);
            kr0 = Kn[tid];
            if (tid < 224) kr1 = Kn[tid + 256];
            vr0 = Vn[tid];
            vr1 = Vn[tid + 256];
            if (tid < 112) vr2 = Vn[tid + 512];
        }

        _Float16* Kb = (b & 1) ? Ks1 : Ks0;
        _Float16* Vb = (b & 1) ? Vs1 : Vs0;
        half8v qb0 = b ? qc0 : qu0;
        half8v qb1 = b ? qc1 : qu1;
        float w = b ? wPh[(size_t)(b - 1) * HW + qrow0 + c] : 1.f;

        // ---- QK^T: A=K rows (key), B=Q ----
        f32x4 s[5];
#pragma unroll
        for (int u = 0; u < 5; ++u) {
            half8v ka0 = *(const half8v*)&Kb[(u * 16 + c) * KSTR + quad * 8];
            half8v ka1 = *(const half8v*)&Kb[(u * 16 + c) * KSTR + 32 + quad * 8];
            f32x4 a = {0.f,0.f,0.f,0.f};
            a = __builtin_amdgcn_mfma_f32_16x16x32_f16(ka0, qb0, a, 0, 0, 0);
            a = __builtin_amdgcn_mfma_f32_16x16x32_f16(ka1, qb1, a, 0, 0, 0);
            s[u] = a;
        }

        // ---- exp + P^T -> LDS ----
#pragma unroll
        for (int u = 0; u < 5; ++u) {
            half4v h = {(_Float16)__expf(s[u][0]), (_Float16)__expf(s[u][1]),
                        (_Float16)__expf(s[u][2]), (_Float16)__expf(s[u][3])};
            *(half4v*)(pl0 + c * PSTR + u * 16 + quad * 4) = h;
        }
        half8v p0 = *(const half8v*)(pl0 + (size_t)c * PSTR + quad * 8);
        half8v p1 = *(const half8v*)(pl0 + (size_t)c * PSTR + 32 + quad * 8);
        half8v p2 = *(const half8v*)(pl0 + (size_t)c * PSTR + 64 + quad * 8);

        // ---- PV: A=V^T rows (d), B=P^T ----
        f32x4 ox[3];
#pragma unroll
        for (int t = 0; t < 3; ++t) {
            half8v va0 = *(const half8v*)&Vb[(t * 16 + c) * VSTR + quad * 8];
            half8v va1 = *(const half8v*)&Vb[(t * 16 + c) * VSTR + 32 + quad * 8];
            half8v va2 = *(const half8v*)&Vb[(t * 16 + c) * VSTR + 64 + quad * 8];
            f32x4 a = {0.f,0.f,0.f,0.f};
            a = __builtin_amdgcn_mfma_f32_16x16x32_f16(va0, p0, a, 0, 0, 0);
            a = __builtin_amdgcn_mfma_f32_16x16x32_f16(va1, p1, a, 0, 0, 0);
            a = __builtin_amdgcn_mfma_f32_16x16x32_f16(va2, p2, a, 0, 0, 0);
            ox[t] = a;
        }

        float l = __shfl(ox[2][0], srcl, 64);

        if (b == 0) {
            float rin = 1.0f / l;
#pragma unroll
            for (int t = 0; t < 3; ++t) {
                if (t < 2 || quad < 2) {
                    half4v h = {(_Float16)(ox[t][0] * rin), (_Float16)(ox[t][1] * rin),
                                (_Float16)(ox[t][2] * rin), (_Float16)(ox[t][3] * rin)};
                    *(half4v*)(Xh + (size_t)(qrow0 + c) * C + head * HD + t * 16 + quad * 4) = h;
                }
            }
        } else {
            float rf = w / l;
#pragma unroll
            for (int t = 0; t < 3; ++t) {
                oacc[t][0] += ox[t][0] * rf;
                oacc[t][1] += ox[t][1] * rf;
                oacc[t][2] += ox[t][2] * rf;
                oacc[t][3] += ox[t][3] * rf;
            }
        }

        // ---- write next batch into the other buffer ----
        if (b + 1 < NB) {
            half8v* Kd = (half8v*)((b & 1) ? Ks0 : Ks1);
            half8v* Vd = (half8v*)((b & 1) ? Vs0 : Vs1);
            Kd[tid] = kr0;
            if (tid < 224) Kd[tid + 256] = kr1;
            Vd[tid] = vr0;
            Vd[tid + 256] = vr1;
            if (tid < 112) Vd[tid + 512] = vr2;
        }
        __syncthreads();
    }

    // write fused cond rows
#pragma unroll
    for (int t = 0; t < 3; ++t) {
        if (t < 2 || quad < 2) {
            half4v h = {(_Float16)oacc[t][0], (_Float16)oacc[t][1],
                        (_Float16)oacc[t][2], (_Float16)oacc[t][3]};
            *(half4v*)(Xh + (size_t)(HW + qrow0 + c) * C + head * HD + t * 16 + quad * 4) = h;
        }
    }
}

// ---------------------------------------------------------------------------
// O-projection f16 MFMA GEMM, B-tile staged in LDS (stride 328 for banks),
// fused epilogue.
// ---------------------------------------------------------------------------
__global__ __launch_bounds__(256) void gemm_oproj_f16(const _Float16* __restrict__ A,
                                                      const _Float16* __restrict__ BT,
                                                      const float* __restrict__ bo,
                                                      const float* __restrict__ wSum,
                                                      float* __restrict__ Out) {
    const int K = C;
    __shared__ _Float16 Bs[64 * 328];
    int tid = threadIdx.x;
    int n0 = blockIdx.x * 64;
    for (int i = tid; i < 64 * 40; i += 256) {
        int row = i / 40, c8 = i - row * 40;
        *(half8v*)&Bs[row * 328 + c8 * 8] =
            *(const half8v*)(BT + (size_t)(n0 + row) * K + c8 * 8);
    }
    __syncthreads();

    int lane = tid & 63, wave = tid >> 6;
    int m0 = blockIdx.y * 64 + wave * 16;
    int lr = lane & 15, kq = (lane >> 4) * 8;
    const _Float16* ap = A + (size_t)(m0 + lr) * K + kq;
    f32x4 acc0 = {0.f,0.f,0.f,0.f}, acc1 = acc0, acc2 = acc0, acc3 = acc0;
#pragma unroll
    for (int k0 = 0; k0 < K; k0 += 32) {
        half8v af = *(const half8v*)(ap + k0);
        half8v b0 = *(const half8v*)&Bs[(0 * 16 + lr) * 328 + k0 + kq];
        half8v b1 = *(const half8v*)&Bs[(1 * 16 + lr) * 328 + k0 + kq];
        half8v b2 = *(const half8v*)&Bs[(2 * 16 + lr) * 328 + k0 + kq];
        half8v b3 = *(const half8v*)&Bs[(3 * 16 + lr) * 328 + k0 + kq];
        acc0 = __builtin_amdgcn_mfma_f32_16x16x32_f16(af, b0, acc0, 0, 0, 0);
        acc1 = __builtin_amdgcn_mfma_f32_16x16x32_f16(af, b1, acc1, 0, 0, 0);
        acc2 = __builtin_amdgcn_mfma_f32_16x16x32_f16(af, b2, acc2, 0, 0, 0);
        acc3 = __builtin_amdgcn_mfma_f32_16x16x32_f16(af, b3, acc3, 0, 0, 0);
    }
    int rb = m0 + ((lane >> 4) << 2);
    f32x4 accs[4] = {acc0, acc1, acc2, acc3};
#pragma unroll
    for (int t = 0; t < 4; ++t) {
        int col = n0 + t * 16 + lr;
        float bv = bo[col];
#pragma unroll
        for (int r = 0; r < 4; ++r) {
            int row = rb + r;
            float v = accs[t][r];
            if (row < HW) {
                v += bv;
            } else {
                float ws = wSum[row - HW];
                v = (v + bv * ws) / (ws + 1e-6f);
            }
            Out[(size_t)row * C + col] = v;
        }
    }
}

// ---------------------------------------------------------------------------
// Launch: 4 dispatches.
// ---------------------------------------------------------------------------
extern "C" void kernel_launch(void* const* d_in, const int* in_sizes, int n_in,
                              void* d_out, int out_size, void* d_ws, size_t ws_size,
                              hipStream_t stream) {
    const float* hs   = (const float*)d_in[0];
    const float* ehs  = (const float*)d_in[1];
    const float* bbox = (const float*)d_in[2];
    const float* Wq   = (const float*)d_in[3];
    const float* Wk   = (const float*)d_in[4];
    const float* Wv   = (const float*)d_in[5];
    const float* Wo   = (const float*)d_in[6];
    const float* bo   = (const float*)d_in[7];
    float* out = (float*)d_out;

    float* wPh  = (float*)d_ws;                          // 9*4096
    float* wSum = wPh + (size_t)9 * HW;                  // 4096
    _Float16* hsH  = (_Float16*)(wSum + HW);             // 8192*320
    _Float16* ehsH = hsH + (size_t)2 * HW * C;           // 770*768
    _Float16* WqT  = ehsH + (size_t)NB * L * CX;         // 320*320
    _Float16* WkvT = WqT + (size_t)C * C;                // 640*768
    _Float16* WoT  = WkvT + (size_t)KVC * CX;            // 320*320
    _Float16* Khp  = WoT + (size_t)C * C;                // 80*80*KSTR
    _Float16* VTg  = Khp + (size_t)80 * KBH;             // 80*48*VSTR
    _Float16* Xh   = VTg + (size_t)80 * VBH;             // 8192*320

    prep_kernel<<<dim3(NPREP), 256, 0, stream>>>(bbox, hs, ehs, Wq, Wk, Wv, Wo,
                                                 wPh, wSum, hsH, ehsH, WqT, WkvT, WoT,
                                                 VTg, Khp);
    gemm_kv<<<dim3(KVC / 64, (NB * L + 63) / 64), 256, 0, stream>>>(ehsH, WkvT, Khp, VTg);
    attn_mfma<<<dim3(NH * 64), 256, 0, stream>>>(hsH, WqT, Khp, VTg, wPh, Xh);
    gemm_oproj_f16<<<dim3(C / 64, (2 * HW) / 64), 256, 0, stream>>>(Xh, WoT, bo, wSum, out);
}